// Round 12
// baseline (1051.851 us; speedup 1.0000x reference)
//
#include <hip/hip_runtime.h>

#define TT 1024
#define BB 32
#define DD 384
#define NE 1025
#define ALPHA_ 0.1f
#define TC 4
#define KSTEP 64
#define NKS 6
#define MROWS 128
#define PADK 72
#define NTHR 512

typedef __attribute__((ext_vector_type(8))) short short8;
typedef __attribute__((ext_vector_type(8))) unsigned short ushort8;
typedef __attribute__((ext_vector_type(4))) float f32x4;

__device__ __forceinline__ unsigned short f2bf(float f) {
    unsigned int u = __float_as_uint(f);
    unsigned int r = u + 0x7fffu + ((u >> 16) & 1u);
    return (unsigned short)(r >> 16);
}

__device__ __host__ __forceinline__ int chunks_of(int j, int* Lout) {
    int k = __builtin_ctz(j);
    int life = (1 << (k + 2)) + 1;
    int jend = j + life - 1; if (jend > TT) jend = TT;
    int L = jend - j + 1;
    *Lout = L;
    return (L + TC - 1) / TC;
}

// async global->LDS, 16B per lane, LDS dst = uniform base + lane*16
__device__ __forceinline__ void gl16(const void* g, void* l) {
    __builtin_amdgcn_global_load_lds(
        (const __attribute__((address_space(1))) void*)g,
        (__attribute__((address_space(3))) void*)l, 16, 0, 0);
}

// sum over lanes 0..31 (lanes 32..63 must be 0), broadcast via readlane
__device__ __forceinline__ float dppsum32(float v) {
    float t;
    t = __int_as_float(__builtin_amdgcn_update_dpp(0, __float_as_int(v), 0x111, 0xf, 0xf, true)); v += t;
    t = __int_as_float(__builtin_amdgcn_update_dpp(0, __float_as_int(v), 0x112, 0xf, 0xf, true)); v += t;
    t = __int_as_float(__builtin_amdgcn_update_dpp(0, __float_as_int(v), 0x114, 0xf, 0xf, true)); v += t;
    t = __int_as_float(__builtin_amdgcn_update_dpp(0, __float_as_int(v), 0x118, 0xf, 0xf, true)); v += t;
    t = __int_as_float(__builtin_amdgcn_update_dpp(0, __float_as_int(v), 0x142, 0xf, 0xf, true)); v += t;
    return __int_as_float(__builtin_amdgcn_readlane(__float_as_int(v), 31));
}

// ---------------- tier1 merged setup: table | pref | perm16 ----------------
__global__ void setup_all(int* __restrict__ table, int* __restrict__ pref,
                          short* __restrict__ perm16,
                          const int* __restrict__ aidx, const float* __restrict__ amask,
                          int K) {
    __shared__ int sc[1024];
    int b = blockIdx.x, t = threadIdx.x;
    if (b == 0) {
        int j = t + 1;
        int L; int nc = chunks_of(j, &L);
        int start = 0;
        for (int jp = 1; jp < j; ++jp) { int Lp; start += chunks_of(jp, &Lp); }
        for (int c = 0; c < nc; ++c) {
            int cnt = L - c * TC; if (cnt > TC) cnt = TC;
            int* e = table + 3 * (start + c);
            e[0] = j - 1;
            e[1] = (j - 1) + c * TC;
            e[2] = cnt;
        }
    } else if (b == 1) {
        int c = 0;
        for (int kk = 0; kk < K; ++kk) c += (amask[t * K + kk] > 0.f) ? 1 : 0;
        sc[t] = c;
        __syncthreads();
        for (int off = 1; off < 1024; off <<= 1) {
            int v = (t >= off) ? sc[t - off] : 0;
            __syncthreads();
            sc[t] += v;
            __syncthreads();
        }
        if (t == 0) pref[0] = 0;
        pref[t + 1] = sc[t];
    } else {
        int t0 = b - 2;                 // 0..1024
        int l = t;
        if (l < 32) {
            short enc = 63;
            if (t0 >= 1 && t0 <= TT - 1 && l < K && amask[t0 * K + l] > 0.f) {
                int sp = aidx[t0 * K + l];
                if (sp == t0) enc = (short)(-sp);
                else {
                    for (int kk = 0; kk < K; ++kk)
                        if (aidx[(t0 - 1) * K + kk] == sp) { enc = (short)kk; break; }
                }
            }
            perm16[t0 * 32 + l] = enc;
        }
    }
}

// ---------------- tier1: W -> bf16 fragment-permuted, direct gather (no LDS) ----------------
__global__ __launch_bounds__(512)
void conv_w2(const float* __restrict__ W, unsigned short* __restrict__ Wperm) {
    int db = blockIdx.x;          // 0..11
    int j  = blockIdx.y;          // 0..1023
    int tid = threadIdx.x, l = tid & 63, w8 = tid >> 6;
    const float* Wj = W + (size_t)j * (DD * DD)
                        + (size_t)(db * 32 + (l >> 4) * 8) * DD + (l & 15);
#pragma unroll
    for (int it = 0; it < 3; ++it) {
        int eblk = it * 8 + w8;                 // 0..23
        const float* src = Wj + eblk * 16;
        ushort8 h;
#pragma unroll
        for (int k = 0; k < 8; ++k) h[k] = f2bf(src[(size_t)k * DD]);
        *(ushort8*)&Wperm[(((size_t)j * 12 + db) * 24 + eblk) * 512 + l * 8] = h;
    }
}

// ---------------- tier1: merged conv_x2 + conv_tgt (both read only x) ----------------
__global__ __launch_bounds__(512)
void conv_xt(const float* __restrict__ x, unsigned short* __restrict__ xperm,
             unsigned short* __restrict__ tgtbf) {
    int bidx = blockIdx.x;
    int tid = threadIdx.x;
    if (bidx < TT) {
        // conv_x2: x -> bf16, fragment-permuted, direct gather
        int t = bidx;
        int l = tid & 63, w8 = tid >> 6;
#pragma unroll
        for (int it = 0; it < 3; ++it) {
            int T = it * 8 + w8;                    // 0..23 = bb*12 + db
            int bb = T / 12, db = T - bb * 12;
            const float* src = x + ((size_t)(bb * 16 + (l & 15)) * TT + t) * DD
                                 + db * 32 + (l >> 4) * 8;
            float4 f0 = *(const float4*)src;
            float4 f1 = *(const float4*)(src + 4);
            ushort8 h;
            h[0] = f2bf(f0.x); h[1] = f2bf(f0.y); h[2] = f2bf(f0.z); h[3] = f2bf(f0.w);
            h[4] = f2bf(f1.x); h[5] = f2bf(f1.y); h[6] = f2bf(f1.z); h[7] = f2bf(f1.w);
            *(ushort8*)&xperm[(size_t)t * 12288 + T * 512 + l * 8] = h;
        }
    } else {
        // conv_tgt: softmax(x) targets as bf16
        __shared__ unsigned short sL[8 * 384];
        int blk = bidx - TT;
        int wid = tid >> 6, lane = tid & 63;
        size_t row = (size_t)blk * 8 + wid;
        const float* xr = x + row * DD;
        float v[6]; float m = -1e30f;
#pragma unroll
        for (int i = 0; i < 6; ++i) { v[i] = xr[lane + 64 * i]; m = fmaxf(m, v[i]); }
#pragma unroll
        for (int d = 1; d < 64; d <<= 1) m = fmaxf(m, __shfl_xor(m, d));
        float s = 0.f;
#pragma unroll
        for (int i = 0; i < 6; ++i) { v[i] = __expf(v[i] - m); s += v[i]; }
#pragma unroll
        for (int d = 1; d < 64; d <<= 1) s += __shfl_xor(s, d);
        float rz = 1.0f / s;
#pragma unroll
        for (int i = 0; i < 6; ++i) sL[wid * 384 + lane + 64 * i] = f2bf(v[i] * rz);
        __syncthreads();
        unsigned int* dst = (unsigned int*)(tgtbf + (size_t)blk * 8 * 384);
        const unsigned int* s32 = (const unsigned int*)sL;
#pragma unroll
        for (int i = 0; i < 3; ++i) dst[i * 512 + tid] = s32[i * 512 + tid];
    }
}

// standalone conv_tgt (tier2)
__global__ void conv_tgt(const float* __restrict__ x, unsigned short* __restrict__ tgtbf) {
    __shared__ unsigned short sL[8 * 384];
    int tid = threadIdx.x;
    int wid = tid >> 6, lane = tid & 63;
    size_t row = (size_t)blockIdx.x * 8 + wid;
    const float* xr = x + row * DD;
    float v[6]; float m = -1e30f;
#pragma unroll
    for (int i = 0; i < 6; ++i) { v[i] = xr[lane + 64 * i]; m = fmaxf(m, v[i]); }
#pragma unroll
    for (int d = 1; d < 64; d <<= 1) m = fmaxf(m, __shfl_xor(m, d));
    float s = 0.f;
#pragma unroll
    for (int i = 0; i < 6; ++i) { v[i] = __expf(v[i] - m); s += v[i]; }
#pragma unroll
    for (int d = 1; d < 64; d <<= 1) s += __shfl_xor(s, d);
    float rz = 1.0f / s;
#pragma unroll
    for (int i = 0; i < 6; ++i) sL[wid * 384 + lane + 64 * i] = f2bf(v[i] * rz);
    __syncthreads();
    unsigned int* dst = (unsigned int*)(tgtbf + (size_t)blockIdx.x * 8 * 384);
    const unsigned int* s32 = (const unsigned int*)sL;
#pragma unroll
    for (int i = 0; i < 3; ++i) dst[i * 512 + tid] = s32[i * 512 + tid];
}

// ---------------- phase A: register-direct barrier-free GEMM + CE epilogue ----------------
// Round-12: the fragment-permuted layout makes each lane's MFMA operand a
// contiguous 16B at tile*1024B + lane*16B — LDS staging was a pass-through.
// Load fragments global->VGPR per wave: ZERO barriers, ZERO LDS in the K-loop;
// per-wave vmcnt self-sync. 4x tile re-read lands in L1/L2 (32KB/k-step
// working set fits L1). LDS now ~7KB (epilogue stats only).
// Plain __launch_bounds__(1024) — round-5's (1024,8) spilled acc. Never re-add.
__global__ __launch_bounds__(1024)
void gemmA(const unsigned short* __restrict__ xperm,
           const unsigned short* __restrict__ Wperm,
           const float* __restrict__ bias,
           const int* __restrict__ aidx,
           const unsigned short* __restrict__ tgtbf,
           float* __restrict__ Epad,
           const int* __restrict__ table, int nblk, int K,
           const int* __restrict__ pref,
           unsigned short* __restrict__ outs)
{
    __shared__ float sStat[128 * 12];
    __shared__ float sRow[128];
    __shared__ int sKK[TC];
    __shared__ int sSlot[TC];

    int bid = blockIdx.x;
    int q8 = nblk >> 3, r8 = nblk & 7;
    int xcd = bid & 7, pos = bid >> 3;
    int lb = (xcd < r8 ? xcd * (q8 + 1) : r8 * (q8 + 1) + (xcd - r8) * q8) + pos;

    int s = table[3 * lb], t0s = table[3 * lb + 1], cnt = table[3 * lb + 2];

    int tid = threadIdx.x;
    int wid = tid >> 6, lane = tid & 63;
    int waveM = wid >> 2, waveN = wid & 3;
    int lc = lane & 15, lg = lane >> 4;

    // this wave's timestep (A tiles mf=0,1 share tc=waveM; bb=mf)
    int tW = t0s + waveM; if (tW > TT - 1) tW = TT - 1;

    // slot/kk search in prologue (ordered by post-K-loop __syncthreads)
    if (tid < TC) {
        int kk = 0, slot = 0;
        if (tid < cnt) {
            int t = t0s + tid;
            for (int k2 = 0; k2 < K; ++k2)
                if (aidx[t * K + k2] == s) { kk = k2; break; }
            if (pref) slot = pref[t] + kk;
        }
        sKK[tid] = kk;
        sSlot[tid] = slot;
    }

    f32x4 acc[2][6];
    f32x4 zz = {0.f, 0.f, 0.f, 0.f};
#pragma unroll
    for (int m = 0; m < 2; ++m)
#pragma unroll
        for (int n = 0; n < 6; ++n) acc[m][n] = zz;

    // per-lane fragment base pointers (contiguous 16B per lane in perm layout)
    const unsigned short* aPtr = xperm + ((size_t)tW * 24) * 512 + lane * 8;
    const unsigned short* bPtr = Wperm + (size_t)s * (12 * 24 * 512)
                                       + (size_t)(waveN * 6) * 512 + lane * 8;

#pragma unroll
    for (int ks = 0; ks < 12; ++ks) {
        short8 af0 = *(const short8*)(aPtr + (size_t)ks * 512);            // bb=0
        short8 af1 = *(const short8*)(aPtr + (size_t)(12 + ks) * 512);     // bb=1
        short8 bf[6];
#pragma unroll
        for (int nf = 0; nf < 6; ++nf)
            bf[nf] = *(const short8*)(bPtr + (size_t)ks * 12288 + nf * 512);
        __builtin_amdgcn_s_setprio(1);
#pragma unroll
        for (int nf = 0; nf < 6; ++nf) {
            acc[0][nf] = __builtin_amdgcn_mfma_f32_16x16x32_bf16(af0, bf[nf], acc[0][nf], 0, 0, 0);
            acc[1][nf] = __builtin_amdgcn_mfma_f32_16x16x32_bf16(af1, bf[nf], acc[1][nf], 0, 0, 0);
        }
        __builtin_amdgcn_s_setprio(0);
    }
    __syncthreads();   // orders sKK/sSlot writes before epilogue reads

    // ---- epilogue (2-phase, stride-12 stats): bias -> outs -> psum/pdot -> E ----
#pragma unroll
    for (int nf = 0; nf < 6; ++nf) {
        float be = bias[(size_t)s * DD + waveN * 96 + nf * 16 + lc];
#pragma unroll
        for (int mf = 0; mf < 2; ++mf)
#pragma unroll
            for (int rr = 0; rr < 4; ++rr) acc[mf][nf][rr] += be;
    }
    // frag-packed outs store: per (mf,nf) one 8B uint2 at [slot][c2][lane]
    if (outs && waveM < cnt) {
        unsigned short* ob = outs + (size_t)sSlot[waveM] * 12288;
#pragma unroll
        for (int mf = 0; mf < 2; ++mf)
#pragma unroll
            for (int nf = 0; nf < 6; ++nf) {
                int c2 = mf * 24 + waveN * 6 + nf;
                unsigned int lo, hi;
                asm("v_cvt_pk_bf16_f32 %0, %1, %2" : "=v"(lo)
                    : "v"(acc[mf][nf][0]), "v"(acc[mf][nf][1]));
                asm("v_cvt_pk_bf16_f32 %0, %1, %2" : "=v"(hi)
                    : "v"(acc[mf][nf][2]), "v"(acc[mf][nf][3]));
                uint2 pk; pk.x = lo; pk.y = hi;
                *(uint2*)&ob[c2 * 256 + lane * 4] = pk;
            }
    }
    // psum/pdot without max-subtraction (outs ~ N(0,1): exp overflow impossible)
#pragma unroll
    for (int mf = 0; mf < 2; ++mf)
#pragma unroll
        for (int rr = 0; rr < 4; ++rr) {
            int row = waveM * 32 + mf * 16 + lg * 4 + rr;
            int b = row & 31;
            const unsigned short* tg = tgtbf + ((size_t)b * TT + tW) * DD;
            float psum = 0.f, pdot = 0.f;
#pragma unroll
            for (int nf = 0; nf < 6; ++nf) {
                int e = waveN * 96 + nf * 16 + lc;
                float a = acc[mf][nf][rr];
                psum += __expf(a);
                float tv = __uint_as_float(((unsigned int)tg[e]) << 16);
                pdot += tv * a;
            }
#pragma unroll
            for (int d = 1; d < 16; d <<= 1) { psum += __shfl_xor(psum, d); pdot += __shfl_xor(pdot, d); }
            if (lc == 0) { sStat[row * 12 + waveN] = psum; sStat[row * 12 + 4 + waveN] = pdot; }
        }
    __syncthreads();
    if (wid == 0) {
#pragma unroll
        for (int h = 0; h < 2; ++h) {
            int row = lane + h * 64;
            const f32x4 pp = *(const f32x4*)&sStat[row * 12];
            const f32x4 dd = *(const f32x4*)&sStat[row * 12 + 4];
            float S = pp[0] + pp[1] + pp[2] + pp[3];
            float Dt = dd[0] + dd[1] + dd[2] + dd[3];
            sRow[row] = __logf(S) - Dt;
        }
    }
    __syncthreads();
    if (wid == 0) {
#pragma unroll
        for (int pph = 0; pph < 2; ++pph) {
            int tc = pph * 2 + (lane >> 5);
            int b = lane & 31;
            float v = (tc < cnt) ? sRow[tc * 32 + b] : 0.f;
#pragma unroll
            for (int d = 1; d < 32; d <<= 1) v += __shfl_xor(v, d);
            if (b == 0 && tc < cnt) {
                float loss = v * (1.0f / 32.0f);
                float E = __expf(-ALPHA_ * loss);
                int t0 = t0s + tc;
                Epad[t0 * 32 + sKK[tc]] = E;
            }
        }
    }
}

// ---------------- recur3: LDS-staged serial recurrence ----------------
__global__ __launch_bounds__(256)
void recur3(const float* __restrict__ Epad, const short* __restrict__ perm16,
            const int* __restrict__ aidx, const float* __restrict__ amask,
            float* __restrict__ wraw, int K) {
    __shared__ __align__(16) float sE[2][4096];
    __shared__ __align__(16) short sP[2][4160];
    int tid = threadIdx.x, wid = tid >> 6, lane = tid & 63;
    int l = lane;

    auto stageCh = [&](int buf, int c) {
        const float* eb = Epad + c * 4096;
#pragma unroll
        for (int i = wid; i < 16; i += 4)
            gl16(eb + i * 256 + lane * 4, &sE[buf][i * 256]);
        const short* pb = perm16 + (c * 128 + 1) * 32;
#pragma unroll
        for (int i = wid; i < 8; i += 4)
            gl16(pb + i * 512 + lane * 8, &sP[buf][32 + i * 512]);
    };

    stageCh(0, 0);
    __syncthreads();

    float pr = 0.f;
    if (l < K && amask[l] > 0.f && aidx[l] == 0) pr = 1.f;

    int buf = 0;
    for (int c = 0; c < 8; ++c) {
        if (c < 7) stageCh(buf ^ 1, c + 1);
        if (wid == 0) {
            float curE = (l < 32) ? sE[buf][l] : 0.f;
            short curP = (l < 32) ? sP[buf][32 + l] : (short)63;
            for (int tl = 0; tl < 128; ++tl) {
                float nE = 0.f; short nP = 63;
                if (tl < 127) {
                    nE = sE[buf][(tl + 1) * 32 + (l & 31)];
                    nP = sP[buf][(tl + 2) * 32 + (l & 31)];
                }
                int t = c * 128 + tl;
                if (l < 32) wraw[t * 32 + l] = pr;
                float qv = pr * curE;
                float S2 = dppsum32(qv);
                float pn = qv / S2;
                int pe = (l < 32) ? (int)curP : 63;
                int src = pe >= 0 ? pe : 0;
                float sv = __shfl(pn, src);
                pr = (pe >= 0) ? sv : (1.0f / (float)(-pe));
                curE = (l < 32) ? nE : 0.f;
                curP = nP;
            }
        }
        __syncthreads();
        buf ^= 1;
    }
}

// ---------------- normalize wraw -> w (tier2 only) ----------------
__global__ void wnorm(float* __restrict__ w) {
    int tid = threadIdx.x;
    int wid = tid >> 6, lane = tid & 63;
    int half = lane >> 5, l = lane & 31;
    int t = blockIdx.x * 8 + wid * 2 + half;
    float v = w[t * 32 + l];
    float s = v;
#pragma unroll
    for (int d = 1; d < 32; d <<= 1) s += __shfl_xor(s, d);
    w[t * 32 + l] = v / s;
}

// ---------------- mixout (frag layout, fused weight-normalize) ----------------
__global__ __launch_bounds__(512)
void mixout(const unsigned short* __restrict__ outs, const float* __restrict__ wraw,
            const int* __restrict__ pref, float* __restrict__ y) {
    int t = blockIdx.x;
    __shared__ float sW[32];
    int tid = threadIdx.x;
    if (tid < 32) {
        float v = wraw[t * 32 + tid];       // dead lanes are exact 0
        float s = v;
#pragma unroll
        for (int d = 1; d < 32; d <<= 1) s += __shfl_xor(s, d);
        sW[tid] = v / s;
    }
    __syncthreads();
    int p0 = pref[t];
    int L = pref[t + 1] - p0;
    float acc[24];
#pragma unroll
    for (int i = 0; i < 24; ++i) acc[i] = 0.f;
    const ushort8* base = (const ushort8*)(outs + (size_t)p0 * 12288);
    for (int kk = 0; kk < L; ++kk) {
        float w = sW[kk];
        const ushort8* sp = base + (size_t)kk * 1536;
#pragma unroll
        for (int pass = 0; pass < 3; ++pass) {
            ushort8 v = sp[pass * 512 + tid];
#pragma unroll
            for (int j = 0; j < 8; ++j)
                acc[pass * 8 + j] += w * __uint_as_float(((unsigned int)v[j]) << 16);
        }
    }
    // decode frag layout: pos = idx*8+j; c2 = idx>>5; lane = (idx*2 + (j>>2))&63; rr = j&3
#pragma unroll
    for (int pass = 0; pass < 3; ++pass) {
        int idx = pass * 512 + tid;
        int c2 = idx >> 5;
        int lane0 = (idx * 2) & 63;
        int mf = (c2 >= 24) ? 1 : 0;
        int rem = c2 - mf * 24;
        int wN = rem / 6, nf = rem - wN * 6;
        int e0 = wN * 96 + nf * 16 + (lane0 & 15);      // lane0 even -> e0, e0+1 pair
        int bb = mf * 16 + (lane0 >> 4) * 4;
#pragma unroll
        for (int r = 0; r < 4; ++r) {
            int b = bb + r;
            float2 st;
            st.x = acc[pass * 8 + r];        // (b, e0)   from lane0
            st.y = acc[pass * 8 + 4 + r];    // (b, e0+1) from lane0+1
            *(float2*)&y[((size_t)b * TT + t) * DD + e0] = st;
        }
    }
}

// ================= tier2 helpers (round-3 verified) =================
__global__ void setup_blocks(int* __restrict__ table) {
    int j = threadIdx.x + 1;
    int L; int nc = chunks_of(j, &L);
    int start = 0;
    for (int jp = 1; jp < j; ++jp) { int Lp; start += chunks_of(jp, &Lp); }
    for (int c = 0; c < nc; ++c) {
        int cnt = L - c * TC; if (cnt > TC) cnt = TC;
        int* e = table + 3 * (start + c);
        e[0] = j - 1;
        e[1] = (j - 1) + c * TC;
        e[2] = cnt;
    }
}

__global__ void setup_union(int* __restrict__ uCount, int* __restrict__ uList) {
    int c = threadIdx.x;
    int t1 = 2 * c + 1, t2 = 2 * c + 2;
    int n = 0;
    for (int j = 1; j <= t2 && j <= TT; ++j) {
        int k = __builtin_ctz(j);
        int life = (1 << (k + 2)) + 1;
        if (j + life - 1 >= t1) { if (n < 32) uList[c * 32 + n] = j - 1; n++; }
    }
    uCount[c] = n > 32 ? 32 : n;
}

__global__ void setup_perm3(const int* __restrict__ aidx, const float* __restrict__ amask,
                            short* __restrict__ perm16, int K) {
    int t0 = blockIdx.x;
    int l = threadIdx.x;
    short enc = 63;
    if (t0 >= 1 && t0 <= TT - 1 && l < K && amask[t0 * K + l] > 0.f) {
        int sp = aidx[t0 * K + l];
        if (sp == t0) enc = (short)(-sp);
        else {
            for (int kk = 0; kk < K; ++kk)
                if (aidx[(t0 - 1) * K + kk] == sp) { enc = (short)kk; break; }
        }
    }
    perm16[t0 * 32 + l] = enc;
}

__global__ void conv_w(const float* __restrict__ W, unsigned short* __restrict__ Wperm) {
    int db = blockIdx.x;
    int j  = blockIdx.y;
    __shared__ __align__(16) unsigned short sL[12288];
    int tid = threadIdx.x;
    int r = tid >> 4, q = tid & 15;
    const float* src = W + (size_t)j * (DD * DD) + (size_t)(db * 32 + r) * DD + q * 24;
#pragma unroll
    for (int i = 0; i < 6; ++i) {
        float4 f = *(const float4*)(src + i * 4);
        int e0 = q * 24 + i * 4;
        float fv[4] = {f.x, f.y, f.z, f.w};
#pragma unroll
        for (int m = 0; m < 4; ++m) {
            int e = e0 + m;
            int off = (e >> 4) * 512 + (r >> 3) * 128 + (e & 15) * 8 + (r & 7);
            sL[off] = f2bf(fv[m]);
        }
    }
    __syncthreads();
    ushort8* dst = (ushort8*)(Wperm + ((size_t)j * 12 + db) * 12288);
    const ushort8* s8 = (const ushort8*)sL;
#pragma unroll
    for (int i = 0; i < 3; ++i) dst[tid * 3 + i] = s8[tid * 3 + i];
}

__global__ void conv_x(const float* __restrict__ x, unsigned short* __restrict__ xperm) {
    int t = blockIdx.x;
    __shared__ __align__(16) unsigned short sL[12288];
    int tid = threadIdx.x;
    int b = tid >> 4, q = tid & 15;
    const float* src = x + ((size_t)b * TT + t) * DD + q * 24;
#pragma unroll
    for (int i = 0; i < 6; ++i) {
        float4 f = *(const float4*)(src + i * 4);
        int d0 = q * 24 + i * 4;
        float fv[4] = {f.x, f.y, f.z, f.w};
#pragma unroll
        for (int m = 0; m < 4; ++m) {
            int d = d0 + m;
            int off = ((b >> 4) * 12 + (d >> 5)) * 512 + ((d >> 3) & 3) * 128 + (b & 15) * 8 + (d & 7);
            sL[off] = f2bf(fv[m]);
        }
    }
    __syncthreads();
    ushort8* dst = (ushort8*)(xperm + (size_t)t * 12288);
    const ushort8* s8 = (const ushort8*)sL;
#pragma unroll
    for (int i = 0; i < 3; ++i) dst[tid * 3 + i] = s8[tid * 3 + i];
}

__global__ __launch_bounds__(1024)
void gemmC(const unsigned short* __restrict__ xperm,
           const unsigned short* __restrict__ Wperm,
           const float* __restrict__ bias,
           const int* __restrict__ aidx,
           const float* __restrict__ wts32,
           const int* __restrict__ uCount, const int* __restrict__ uList,
           float* __restrict__ y, int K)
{
    __shared__ __align__(16) unsigned short sAF[24576];
    __shared__ __align__(16) unsigned short sB[2][12288];
    __shared__ float sWu[64];
    __shared__ int   sUL[32];
    __shared__ float sBv[768];

    int nb = gridDim.x;
    int bid = blockIdx.x;
    int q8 = nb >> 3, r8 = nb & 7;
    int xcd = bid & 7, pos = bid >> 3;
    int c = (xcd < r8 ? xcd * (q8 + 1) : r8 * (q8 + 1) + (xcd - r8) * q8) + pos;

    int t0 = c * 2;
    int tid = threadIdx.x, wid = tid >> 6, lane = tid & 63;
    int waveM = wid >> 2, waveN = wid & 3;
    int lc = lane & 15, lg = lane >> 4;
    int tcw = waveM >> 1, bbw = waveM & 1;

    int uc = uCount[c];
    if (tid < uc) sUL[tid] = uList[c * 32 + tid];
#pragma unroll
    for (int i = 0; i < 3; ++i) {
        int T = wid * 3 + i;
        int tc = T / 24, bb = (T / 12) & 1, db = T % 12;
        const unsigned short* src = xperm + ((size_t)(t0 + tc) * 24 + bb * 12 + db) * 512 + lane * 8;
        gl16(src, &sAF[T * 512]);
    }
    __syncthreads();
    if (tid < 2 * uc) {
        int u = tid >> 1, tc = tid & 1;
        int j = sUL[u];
        float wv = 0.f;
        for (int kk = 0; kk < K; ++kk)
            if (aidx[(t0 + tc) * K + kk] == j) { wv = wts32[(t0 + tc) * 32 + kk]; break; }
        sWu[u * 2 + tc] = wv;
    }
    __syncthreads();
    {
        size_t wb = (size_t)sUL[0] * (12 * 24 * 512);
        const unsigned short* b0 = Wperm + wb + (size_t)wid * 512 + lane * 8;
        gl16(b0, &sB[0][wid * 512]);
        if (wid < 8) {
            const unsigned short* b1 = Wperm + wb + (size_t)(16 + wid) * 512 + lane * 8;
            gl16(b1, &sB[0][(16 + wid) * 512]);
        }
    }
    for (int i = tid; i < 768; i += 1024) {
        int tc = (i >= 384) ? 1 : 0; int e = i - tc * 384;
        float a = 0.f;
        for (int u = 0; u < uc; ++u) a += sWu[u * 2 + tc] * bias[(size_t)sUL[u] * DD + e];
        sBv[i] = a;
    }
    __syncthreads();

    f32x4 accY[6], accE[6];
    f32x4 zz = {0.f, 0.f, 0.f, 0.f};
#pragma unroll
    for (int n = 0; n < 6; ++n) { accY[n] = zz; accE[n] = zz; }

    int buf = 0;
    for (int u = 0; u < uc; ++u) {
        float wv = sWu[u * 2 + tcw];
        bool act = (wv != 0.f);
        for (int ks = 0; ks < 12; ++ks) {
            int nu = u, nk = ks + 1;
            if (nk == 12) { nk = 0; nu = u + 1; }
            if (nu < uc) {
                size_t wb = (size_t)sUL[nu] * (12 * 24 * 512) + (size_t)nk * (24 * 512);
                const unsigned short* b0 = Wperm + wb + (size_t)wid * 512 + lane * 8;
                gl16(b0, &sB[buf ^ 1][wid * 512]);
                if (wid < 8) {
                    const unsigned short* b1 = Wperm + wb + (size_t)(16 + wid) * 512 + lane * 8;
                    gl16(b1, &sB[buf ^ 1][(16 + wid) * 512]);
                }
            }
            if (act) {
                short8 af = *(const short8*)&sAF[(waveM * 12 + ks) * 512 + lane * 8];
#pragma unroll
                for (int nf = 0; nf < 6; ++nf) {
                    short8 bf = *(const short8*)&sB[buf][(waveN * 6 + nf) * 512 + lane * 8];
                    accE[nf] = __builtin_amdgcn_mfma_f32_16x16x32_bf16(af, bf, accE[nf], 0, 0, 0);
                }
            }
            __syncthreads();
            buf ^= 1;
        }
        if (act) {
#pragma unroll
            for (int nf = 0; nf < 6; ++nf)
#pragma unroll
                for (int rr = 0; rr < 4; ++rr) { accY[nf][rr] += wv * accE[nf][rr]; accE[nf][rr] = 0.f; }
        }
    }

    int t = t0 + tcw;
#pragma unroll
    for (int nf = 0; nf < 6; ++nf) {
        int e = waveN * 96 + nf * 16 + lc;
        float bvv = sBv[tcw * 384 + e];
#pragma unroll
        for (int rr = 0; rr < 4; ++rr) {
            int b = bbw * 16 + lg * 4 + rr;
            y[((size_t)b * TT + t) * DD + e] = accY[nf][rr] + bvv;
        }
    }
}

// ================= tier3 fallback (round-1, verified) =================
__global__ void rowstats(const float* __restrict__ x, float* __restrict__ xm,
                         float* __restrict__ rz) {
    int wid = threadIdx.x >> 6;
    int lane = threadIdx.x & 63;
    int row = blockIdx.x * 4 + wid;
    const float* xr = x + (size_t)row * DD;
    float v[6];
    float m = -1e30f;
#pragma unroll
    for (int i = 0; i < 6; ++i) { v[i] = xr[lane + 64 * i]; m = fmaxf(m, v[i]); }
#pragma unroll
    for (int d = 1; d < 64; d <<= 1) m = fmaxf(m, __shfl_xor(m, d));
    float s = 0.f;
#pragma unroll
    for (int i = 0; i < 6; ++i) s += expf(v[i] - m);
#pragma unroll
    for (int d = 1; d < 64; d <<= 1) s += __shfl_xor(s, d);
    if (lane == 0) { xm[row] = m; rz[row] = 1.0f / s; }
}

template<int MODE>
__global__ __launch_bounds__(NTHR)
void gemm_phase(const float* __restrict__ x, const float* __restrict__ W,
                const float* __restrict__ bias, const int* __restrict__ aidx,
                const float* __restrict__ xm, const float* __restrict__ rz,
                const float* __restrict__ wts, float* __restrict__ Earr,
                float* __restrict__ y, const int* __restrict__ table,
                int nblk, int K)
{
    __shared__ __align__(16) unsigned short sA[MROWS * PADK];
    __shared__ __align__(16) unsigned short sB[DD * PADK];
    __shared__ float sRow[MROWS];
    __shared__ float sCoef[TC];

    int bid = blockIdx.x;
    int q = nblk >> 3, r = nblk & 7;
    int xcd = bid & 7, pos = bid >> 3;
    int lb = (xcd < r ? xcd * (q + 1) : r * (q + 1) + (xcd - r) * q) + pos;

    int s = table[3 * lb], t0s = table[3 * lb + 1], cnt = table[3 * lb + 2];

    int tid = threadIdx.x;
    int wid = tid >> 6, lane = tid & 63;
    int waveM = wid >> 2, waveN = wid & 3;
    int lc = lane & 15, lg = lane >> 4;

    if (MODE == 1 && tid < TC) {
        float c = 0.f;
        if (tid < cnt) {
            int t0 = t0s + tid;
            for (int kk = 0; kk < K; ++kk)
                if (aidx[t0 * K + kk] == s) { c = wts[t0 * K + kk]; break; }
        }
        sCoef[tid] = c;
    }

    f32x4 acc[4][6];
    f32x4 zz = {0.f, 0.f, 0.f, 0.f};
#pragma unroll
    for (int i = 0; i < 4; ++i)
#pragma unroll
        for (int n = 0; n < 6; ++n) acc[i][n] = zz;

    const float* Wj = W + (size_t)s * (DD * DD);

    int xr = tid >> 2, xq = tid & 3;
    int xtc = xr >> 5, xb = xr & 31;
    int xt = t0s + xtc; if (xt > TT - 1) xt = TT - 1;
    const float* xrow = x + ((size_t)xb * TT + xt) * DD;

    for (int ks = 0; ks < NKS; ++ks) {
        const int d0 = ks * KSTEP;
        __syncthreads();
        {
            const float4* src = (const float4*)(xrow + d0 + xq * 16);
            float4 f0 = src[0], f1 = src[1], f2 = src[2], f3 = src[3];
            short8 v0, v1;
            v0[0] = (short)f2bf(f0.x); v0[1] = (short)f2bf(f0.y);
            v0[2] = (short)f2bf(f0.z); v0[3] = (short)f2bf(f0.w);
            v0[4] = (short)f2bf(f1.x); v0[5] = (short)f2bf(f1.y);
            v0[6] = (short)f2bf(f1.z); v0[7] = (short)f2bf(f1.w);
            v1[0] = (short)f2bf(f2.x); v1[1] = (short)f2bf(f2.y);
            v1[2] = (short)f2bf(f2.z); v1[3] = (short)f2bf(f2.w);
            v1[4] = (short)f2bf(f3.x); v1[5] = (short)f2bf(f3.y);
            v1[6] = (short)f2bf(f3.z); v1[7] = (short)f2bf(f3.w);
            short8* dst = (short8*)&sA[xr * PADK + xq * 16];
            dst[0] = v0; dst[1] = v1;
        }
        {
            int dbase = d0 + wid * 8;
#pragma unroll
            for (int g = 0; g < 6; ++g) {
                int e = g * 64 + lane;
                const float* col = Wj + (size_t)dbase * DD + e;
                short8 h;
#pragma unroll
                for (int dd = 0; dd < 8; ++dd) h[dd] = (short)f2bf(col[(size_t)dd * DD]);
                *(short8*)&sB[e * PADK + wid * 8] = h;
            }
        }
        __syncthreads();
#pragma unroll
        for (int kh = 0; kh < 2; ++kh) {
            short8 af[4], bfr[6];
#pragma unroll
            for (int mf = 0; mf < 4; ++mf)
                af[mf] = *(const short8*)&sA[(waveM * 64 + mf * 16 + lc) * PADK + kh * 32 + lg * 8];
#pragma unroll
            for (int nf = 0; nf < 6; ++nf)
                bfr[nf] = *(const short8*)&sB[(waveN * 96 + nf * 16 + lc) * PADK + kh * 32 + lg * 8];
#pragma unroll
            for (int mf = 0; mf < 4; ++mf)
#pragma unroll
                for (int nf = 0; nf < 6; ++nf)
                    acc[mf][nf] = __builtin_amdgcn_mfma_f32_16x16x32_bf16(af[mf], bfr[nf], acc[mf][nf], 0, 0, 0);
        }
    }

    if (MODE == 0) {
        __syncthreads();
        float* sStat = (float*)sA;
#pragma unroll
        for (int nf = 0; nf < 6; ++nf) {
            float be = bias[(size_t)s * DD + waveN * 96 + nf * 16 + lc];
#pragma unroll
            for (int mf = 0; mf < 4; ++mf)
#pragma unroll
                for (int rr = 0; rr < 4; ++rr) acc[mf][nf][rr] += be;
        }
#pragma unroll
        for (int mf = 0; mf < 4; ++mf)
#pragma unroll
            for (int rr = 0; rr < 4; ++rr) {
                float m = acc[mf][0][rr];
#pragma unroll
                for (int nf = 1; nf < 6; ++nf) m = fmaxf(m, acc[mf][nf][rr]);
#pragma unroll
                for (int d = 1; d < 16; d <<= 1) m = fmaxf(m, __shfl_xor(m, d));
                if (lc == 0) sStat[(waveM * 64 + mf * 16 + lg * 4 + rr) * 12 + waveN] = m;
            }
        __syncthreads();
#pragma unroll
        for (int mf = 0; mf < 4; ++mf)
#pragma unroll
            for (int rr = 0; rr < 4; ++rr) {
                int row = waveM * 64 + mf * 16 + lg * 4 + rr;
                const f32x4 pm = *(const f32x4*)&sStat[row * 12];
                float rmax = fmaxf(fmaxf(pm[0], pm[1]), fmaxf(pm[2], pm[3]));
                int tc = row >> 5, b = row & 31;
                int t = t0s + tc; if (t > TT - 1) t = TT - 1;
                float xmv = xm[b * TT + t];
                float rzv = rz[b * TT + t];
                const float* x2 = x + ((size_t)b * TT + t) * DD;
                float psum = 0.f, pdot = 0.f;
#pragma unroll
                for (int nf = 0; nf < 6; ++nf) {
                    int e = waveN * 96 + nf * 16 + lc;
                    float a = acc[mf][nf][rr];
                    psum += __expf(a - rmax);
                    float tg = __expf(x2[e] - xmv) * rzv;
                    pdot += tg * a;
                }
#pragma unroll
                for (int d = 1; d < 16; d <<= 1) {
                    psum += __shfl_xor(psum, d);
                    pdot += __shfl_xor(pdot, d);
                }
                if (lc == 0) { sStat[row * 12 + 4 + waveN] = psum; sStat[row * 12 + 8 + waveN] = pdot; }
            }
        __syncthreads();
        if (wid == 0) {
#pragma unroll
            for (int h = 0; h < 2; ++h) {
                int row = lane + h * 64;
                const f32x4 mm = *(const f32x4*)&sStat[row * 12];
                const f32x4 pp = *(const f32x4*)&sStat[row * 12 + 4];
                const f32x4 dd = *(const f32x4*)&sStat[row * 12 + 8];
                float rmax = fmaxf(fmaxf(mm[0], mm[1]), fmaxf(mm[2], mm[3]));
                float S = pp[0] + pp[1] + pp[2] + pp[3];
                float Dt = dd[0] + dd[1] + dd[2] + dd[3];
                sRow[row] = rmax + logf(S) - Dt;
            }
        }
        __syncthreads();
        if (wid == 0) {
#pragma unroll
            for (int pph = 0; pph < 2; ++pph) {
                int tc = pph * 2 + (lane >> 5);
                int b = lane & 31;
                float v = (tc < cnt) ? sRow[tc * 32 + b] : 0.f;
#pragma unroll
                for (int d = 1; d < 32; d <<= 1) v += __shfl_xor(v, d);
                if (b == 0 && tc < cnt) {
                    float loss = v * (1.0f / 32.0f);
                    float E = expf(-ALPHA_ * loss);
                    int t0 = t0s + tc;
                    for (int kk = 0; kk < K; ++kk)
                        if (aidx[t0 * K + kk] == s) { Earr[t0 * K + kk] = E; break; }
                }
            }
        }
    } else {
#pragma unroll
        for (int mf = 0; mf < 4; ++mf)
#pragma unroll
            for (int rr = 0; rr < 4; ++rr) {
                int row = waveM * 64 + mf * 16 + lg * 4 + rr;
                int tc = row >> 5, b = row & 31;
                if (tc < cnt) {
                    float c = sCoef[tc];
                    int t = t0s + tc;
                    float* yr = y + ((size_t)b * TT + t) * DD + waveN * 96 + lc;
#pragma unroll
                    for (int nf = 0; nf < 6; ++nf)
                        atomicAdd(yr + nf * 16, c * acc[mf][nf][rr]);
                }
            }
    }
}

__global__ void recurrence(const int* __restrict__ aidx, const float* __restrict__ amask,
                           const float* __restrict__ Earr, float* __restrict__ wts, int K) {
    __shared__ float p[NE];
    int l = threadIdx.x;
    for (int i = l; i < NE; i += 64) p[i] = 0.f;
    __syncthreads();
    if (l == 0) p[0] = 1.f;
    __syncthreads();

    int idxv = TT; float mv = 0.f, Ev = 1.f;
    if (l < K) { idxv = aidx[l]; mv = amask[l]; Ev = Earr[l]; }

    for (int t0 = 0; t0 < TT; ++t0) {
        int idxn = TT; float mn = 0.f, En = 1.f;
        if (t0 + 1 < TT && l < K) {
            idxn = aidx[(t0 + 1) * K + l];
            mn = amask[(t0 + 1) * K + l];
            En = Earr[(t0 + 1) * K + l];
        }
        float pa = (l < K) ? p[idxv] * mv : 0.f;
        float qv = pa * Ev;
        float S1 = pa, S2 = qv;
#pragma unroll
        for (int d = 1; d < 64; d <<= 1) {
            S1 += __shfl_xor(S1, d);
            S2 += __shfl_xor(S2, d);
        }
        float w = pa / S1;
        if (l < K) wts[t0 * K + l] = w;
        float pn = qv / S2;
        __syncthreads();
        if (l < K && mv > 0.f) p[idxv] = pn;
        if (l == 0) p[t0 + 1] = 1.0f / (float)(t0 + 1);
        __syncthreads();
        idxv = idxn; mv = mn; Ev = En;
    }
}

__global__ void bias_init(const float* __restrict__ bias, const int* __restrict__ aidx,
                          const float* __restrict__ wts, float* __restrict__ y, int K) {
    int t0 = blockIdx.x;
    int e = threadIdx.x;
    float acc = 0.f;
    for (int kk = 0; kk < K; ++kk) {
        float w = wts[t0 * K + kk];
        int s = aidx[t0 * K + kk];
        acc += w * bias[(size_t)s * DD + e];
    }
    for (int b = 0; b < BB; ++b)
        y[((size_t)b * TT + t0) * DD + e] = acc;
}

extern "C" void kernel_launch(void* const* d_in, const int* in_sizes, int n_in,
                              void* d_out, int out_size, void* d_ws, size_t ws_size,
                              hipStream_t stream) {
    const float* x = (const float*)d_in[0];
    const float* W = (const float*)d_in[1];
    const float* bv = (const float*)d_in[2];
    const int* aidx = (const int*)d_in[3];
    const float* amask = (const float*)d_in[4];
    float* y = (float*)d_out;
    const int K = in_sizes[3] / TT;

    int nblk = 0, NSLOT = 0;
    for (int j = 1; j <= TT; ++j) { int L; nblk += chunks_of(j, &L); NSLOT += L; }

    size_t szW = (size_t)1024 * 294912;
    size_t szX = (size_t)1024 * 24576;
    size_t szT = (size_t)BB * TT * DD * 2;
    size_t szEp = (size_t)TT * 32 * sizeof(float);
    size_t szWt = (size_t)TT * 32 * sizeof(float);
    size_t szPm = (size_t)(TT + 1) * 32 * sizeof(short);
    size_t szTab = (size_t)6144 * 3 * sizeof(int);
    size_t szUC = 512 * sizeof(int);
    size_t szUL = 512 * 32 * sizeof(int);
    size_t szO  = (size_t)NSLOT * 12288 * 2;
    size_t szPf = (size_t)(TT + 1) * sizeof(int);
    size_t need2 = szW + szX + szT + szEp + szWt + szPm + szTab + szUC + szUL + 256;
    size_t need1 = need2 + szO + szPf;

    if (ws_size >= need1) {
        // ---- tier1 ----
        unsigned char* p = (unsigned char*)d_ws;
        unsigned short* Wperm = (unsigned short*)p; p += szW;
        unsigned short* xperm = (unsigned short*)p; p += szX;
        unsigned short* tgtb  = (unsigned short*)p; p += szT;
        float* Epad = (float*)p; p += szEp;
        float* wts32 = (float*)p; p += szWt;
        short* perm16 = (short*)p; p += szPm;
        int* table  = (int*)p;   p += szTab;
        int* uCnt   = (int*)p;   p += szUC;
        int* uLst   = (int*)p;   p += szUL;
        int* pref   = (int*)p;   p += szPf;
        unsigned short* outs = (unsigned short*)p; p += szO;

        hipLaunchKernelGGL(setup_all, dim3(TT + 3), dim3(1024), 0, stream,
                           table, pref, perm16, aidx, amask, K);
        hipLaunchKernelGGL(conv_w2, dim3(12, 1024), dim3(512), 0, stream, W, Wperm);
        hipLaunchKernelGGL(conv_xt, dim3(TT + BB * TT / 8), dim3(512), 0, stream,
                           x, xperm, tgtb);
        hipMemsetAsync(Epad, 0, szEp, stream);
        hipLaunchKernelGGL(gemmA, dim3(nblk), dim3(1024), 0, stream,
                           xperm, Wperm, bv, aidx, tgtb, Epad, table, nblk, K, pref, outs);
        hipLaunchKernelGGL(recur3, dim3(1), dim3(256), 0, stream,
                           Epad, perm16, aidx, amask, wts32, K);
        hipLaunchKernelGGL(mixout, dim3(TT), dim3(512), 0, stream, outs, wts32, pref, y);
    } else if (ws_size >= need2) {
        // ---- tier2 ----
        unsigned char* p = (unsigned char*)d_ws;
        unsigned short* Wperm = (unsigned short*)p; p += szW;
        unsigned short* xperm = (unsigned short*)p; p += szX;
        unsigned short* tgtb  = (unsigned short*)p; p += szT;
        float* Epad = (float*)p; p += szEp;
        float* wts32 = (float*)p; p += szWt;
        short* perm16 = (short*)p; p += szPm;
        int* table  = (int*)p;   p += szTab;
        int* uCnt   = (int*)p;   p += szUC;
        int* uLst   = (int*)p;   p += szUL;

        hipLaunchKernelGGL(setup_blocks, dim3(1), dim3(1024), 0, stream, table);
        hipLaunchKernelGGL(setup_union, dim3(1), dim3(512), 0, stream, uCnt, uLst);
        hipLaunchKernelGGL(setup_perm3, dim3(TT + 1), dim3(32), 0, stream, aidx, amask, perm16, K);
        hipLaunchKernelGGL(conv_w, dim3(12, 1024), dim3(512), 0, stream, W, Wperm);
        hipLaunchKernelGGL(conv_x, dim3(TT), dim3(512), 0, stream, x, xperm);
        hipLaunchKernelGGL(conv_tgt, dim3(BB * TT / 8), dim3(512), 0, stream, x, tgtb);
        hipMemsetAsync(Epad, 0, szEp, stream);
        hipLaunchKernelGGL(gemmA, dim3(nblk), dim3(1024), 0, stream,
                           xperm, Wperm, bv, aidx, tgtb, Epad, table, nblk, K,
                           (const int*)nullptr, (unsigned short*)nullptr);
        hipLaunchKernelGGL(recur3, dim3(1), dim3(256), 0, stream,
                           Epad, perm16, aidx, amask, wts32, K);
        hipLaunchKernelGGL(wnorm, dim3(TT / 8), dim3(256), 0, stream, wts32);
        hipLaunchKernelGGL(gemmC, dim3(512), dim3(1024), 0, stream,
                           xperm, Wperm, bv, aidx, wts32, uCnt, uLst, y, K);
    } else {
        // ---- tier3 ----
        float* Earr = (float*)d_ws;
        float* wts = Earr + (size_t)TT * K;
        float* xm = wts + (size_t)TT * K;
        float* rz = xm + (size_t)BB * TT;
        int* table = (int*)(rz + (size_t)BB * TT);

        hipLaunchKernelGGL(setup_blocks, dim3(1), dim3(1024), 0, stream, table);
        hipLaunchKernelGGL(rowstats, dim3(BB * TT / 4), dim3(256), 0, stream, x, xm, rz);
        hipLaunchKernelGGL((gemm_phase<0>), dim3(nblk), dim3(NTHR), 0, stream,
                           x, W, bv, aidx, xm, rz, (const float*)nullptr, Earr,
                           (float*)nullptr, table, nblk, K);
        hipLaunchKernelGGL(recurrence, dim3(1), dim3(64), 0, stream, aidx, amask, Earr, wts, K);
        hipLaunchKernelGGL(bias_init, dim3(TT), dim3(DD), 0, stream, bv, aidx, wts, y, K);
        hipLaunchKernelGGL((gemm_phase<1>), dim3(nblk), dim3(NTHR), 0, stream,
                           x, W, bv, aidx, xm, rz, wts, (float*)nullptr, y, table, nblk, K);
    }
}

// Round 13
// 958.913 us; speedup vs baseline: 1.0969x; 1.0969x over previous
//
#include <hip/hip_runtime.h>

#define TT 1024
#define BB 32
#define DD 384
#define NE 1025
#define ALPHA_ 0.1f
#define TC 4
#define KSTEP 64
#define NKS 6
#define MROWS 128
#define PADK 72
#define NTHR 512

typedef __attribute__((ext_vector_type(8))) short short8;
typedef __attribute__((ext_vector_type(8))) unsigned short ushort8;
typedef __attribute__((ext_vector_type(4))) float f32x4;

__device__ __forceinline__ unsigned short f2bf(float f) {
    unsigned int u = __float_as_uint(f);
    unsigned int r = u + 0x7fffu + ((u >> 16) & 1u);
    return (unsigned short)(r >> 16);
}

__device__ __host__ __forceinline__ int chunks_of(int j, int* Lout) {
    int k = __builtin_ctz(j);
    int life = (1 << (k + 2)) + 1;
    int jend = j + life - 1; if (jend > TT) jend = TT;
    int L = jend - j + 1;
    *Lout = L;
    return (L + TC - 1) / TC;
}

// async global->LDS, 16B per lane, LDS dst = uniform base + lane*16
__device__ __forceinline__ void gl16(const void* g, void* l) {
    __builtin_amdgcn_global_load_lds(
        (const __attribute__((address_space(1))) void*)g,
        (__attribute__((address_space(3))) void*)l, 16, 0, 0);
}

// sum over lanes 0..31 (lanes 32..63 must be 0), broadcast via readlane
__device__ __forceinline__ float dppsum32(float v) {
    float t;
    t = __int_as_float(__builtin_amdgcn_update_dpp(0, __float_as_int(v), 0x111, 0xf, 0xf, true)); v += t;
    t = __int_as_float(__builtin_amdgcn_update_dpp(0, __float_as_int(v), 0x112, 0xf, 0xf, true)); v += t;
    t = __int_as_float(__builtin_amdgcn_update_dpp(0, __float_as_int(v), 0x114, 0xf, 0xf, true)); v += t;
    t = __int_as_float(__builtin_amdgcn_update_dpp(0, __float_as_int(v), 0x118, 0xf, 0xf, true)); v += t;
    t = __int_as_float(__builtin_amdgcn_update_dpp(0, __float_as_int(v), 0x142, 0xf, 0xf, true)); v += t;
    return __int_as_float(__builtin_amdgcn_readlane(__float_as_int(v), 31));
}

// ---------------- tier1 merged setup: table | pref | perm16 ----------------
__global__ void setup_all(int* __restrict__ table, int* __restrict__ pref,
                          short* __restrict__ perm16,
                          const int* __restrict__ aidx, const float* __restrict__ amask,
                          int K) {
    __shared__ int sc[1024];
    int b = blockIdx.x, t = threadIdx.x;
    if (b == 0) {
        int j = t + 1;
        int L; int nc = chunks_of(j, &L);
        int start = 0;
        for (int jp = 1; jp < j; ++jp) { int Lp; start += chunks_of(jp, &Lp); }
        for (int c = 0; c < nc; ++c) {
            int cnt = L - c * TC; if (cnt > TC) cnt = TC;
            int* e = table + 3 * (start + c);
            e[0] = j - 1;
            e[1] = (j - 1) + c * TC;
            e[2] = cnt;
        }
    } else if (b == 1) {
        int c = 0;
        for (int kk = 0; kk < K; ++kk) c += (amask[t * K + kk] > 0.f) ? 1 : 0;
        sc[t] = c;
        __syncthreads();
        for (int off = 1; off < 1024; off <<= 1) {
            int v = (t >= off) ? sc[t - off] : 0;
            __syncthreads();
            sc[t] += v;
            __syncthreads();
        }
        if (t == 0) pref[0] = 0;
        pref[t + 1] = sc[t];
    } else {
        int t0 = b - 2;                 // 0..1024
        int l = t;
        if (l < 32) {
            short enc = 63;
            if (t0 >= 1 && t0 <= TT - 1 && l < K && amask[t0 * K + l] > 0.f) {
                int sp = aidx[t0 * K + l];
                if (sp == t0) enc = (short)(-sp);
                else {
                    for (int kk = 0; kk < K; ++kk)
                        if (aidx[(t0 - 1) * K + kk] == sp) { enc = (short)kk; break; }
                }
            }
            perm16[t0 * 32 + l] = enc;
        }
    }
}

// ---------------- tier1: W -> bf16 fragment-permuted, direct gather (no LDS) ----------------
__global__ __launch_bounds__(512)
void conv_w2(const float* __restrict__ W, unsigned short* __restrict__ Wperm) {
    int db = blockIdx.x;          // 0..11
    int j  = blockIdx.y;          // 0..1023
    int tid = threadIdx.x, l = tid & 63, w8 = tid >> 6;
    const float* Wj = W + (size_t)j * (DD * DD)
                        + (size_t)(db * 32 + (l >> 4) * 8) * DD + (l & 15);
#pragma unroll
    for (int it = 0; it < 3; ++it) {
        int eblk = it * 8 + w8;                 // 0..23
        const float* src = Wj + eblk * 16;
        ushort8 h;
#pragma unroll
        for (int k = 0; k < 8; ++k) h[k] = f2bf(src[(size_t)k * DD]);
        *(ushort8*)&Wperm[(((size_t)j * 12 + db) * 24 + eblk) * 512 + l * 8] = h;
    }
}

// ---------------- tier1: merged conv_x2 + conv_tgt (both read only x) ----------------
__global__ __launch_bounds__(512)
void conv_xt(const float* __restrict__ x, unsigned short* __restrict__ xperm,
             unsigned short* __restrict__ tgtbf) {
    int bidx = blockIdx.x;
    int tid = threadIdx.x;
    if (bidx < TT) {
        // conv_x2: x -> bf16, fragment-permuted, direct gather
        int t = bidx;
        int l = tid & 63, w8 = tid >> 6;
#pragma unroll
        for (int it = 0; it < 3; ++it) {
            int T = it * 8 + w8;                    // 0..23 = bb*12 + db
            int bb = T / 12, db = T - bb * 12;
            const float* src = x + ((size_t)(bb * 16 + (l & 15)) * TT + t) * DD
                                 + db * 32 + (l >> 4) * 8;
            float4 f0 = *(const float4*)src;
            float4 f1 = *(const float4*)(src + 4);
            ushort8 h;
            h[0] = f2bf(f0.x); h[1] = f2bf(f0.y); h[2] = f2bf(f0.z); h[3] = f2bf(f0.w);
            h[4] = f2bf(f1.x); h[5] = f2bf(f1.y); h[6] = f2bf(f1.z); h[7] = f2bf(f1.w);
            *(ushort8*)&xperm[(size_t)t * 12288 + T * 512 + l * 8] = h;
        }
    } else {
        // conv_tgt: softmax(x) targets as bf16
        __shared__ unsigned short sL[8 * 384];
        int blk = bidx - TT;
        int wid = tid >> 6, lane = tid & 63;
        size_t row = (size_t)blk * 8 + wid;
        const float* xr = x + row * DD;
        float v[6]; float m = -1e30f;
#pragma unroll
        for (int i = 0; i < 6; ++i) { v[i] = xr[lane + 64 * i]; m = fmaxf(m, v[i]); }
#pragma unroll
        for (int d = 1; d < 64; d <<= 1) m = fmaxf(m, __shfl_xor(m, d));
        float s = 0.f;
#pragma unroll
        for (int i = 0; i < 6; ++i) { v[i] = __expf(v[i] - m); s += v[i]; }
#pragma unroll
        for (int d = 1; d < 64; d <<= 1) s += __shfl_xor(s, d);
        float rz = 1.0f / s;
#pragma unroll
        for (int i = 0; i < 6; ++i) sL[wid * 384 + lane + 64 * i] = f2bf(v[i] * rz);
        __syncthreads();
        unsigned int* dst = (unsigned int*)(tgtbf + (size_t)blk * 8 * 384);
        const unsigned int* s32 = (const unsigned int*)sL;
#pragma unroll
        for (int i = 0; i < 3; ++i) dst[i * 512 + tid] = s32[i * 512 + tid];
    }
}

// standalone conv_tgt (tier2)
__global__ void conv_tgt(const float* __restrict__ x, unsigned short* __restrict__ tgtbf) {
    __shared__ unsigned short sL[8 * 384];
    int tid = threadIdx.x;
    int wid = tid >> 6, lane = tid & 63;
    size_t row = (size_t)blockIdx.x * 8 + wid;
    const float* xr = x + row * DD;
    float v[6]; float m = -1e30f;
#pragma unroll
    for (int i = 0; i < 6; ++i) { v[i] = xr[lane + 64 * i]; m = fmaxf(m, v[i]); }
#pragma unroll
    for (int d = 1; d < 64; d <<= 1) m = fmaxf(m, __shfl_xor(m, d));
    float s = 0.f;
#pragma unroll
    for (int i = 0; i < 6; ++i) { v[i] = __expf(v[i] - m); s += v[i]; }
#pragma unroll
    for (int d = 1; d < 64; d <<= 1) s += __shfl_xor(s, d);
    float rz = 1.0f / s;
#pragma unroll
    for (int i = 0; i < 6; ++i) sL[wid * 384 + lane + 64 * i] = f2bf(v[i] * rz);
    __syncthreads();
    unsigned int* dst = (unsigned int*)(tgtbf + (size_t)blockIdx.x * 8 * 384);
    const unsigned int* s32 = (const unsigned int*)sL;
#pragma unroll
    for (int i = 0; i < 3; ++i) dst[i * 512 + tid] = s32[i * 512 + tid];
}

// ---------------- phase A: 3-buffer single-barrier GEMM + CE epilogue ----------------
// ROUND-11 VERIFIED CONFIG (451us, best of 7 structural variants). 3-buffer
// rotation removes the read-release barrier (at iter k, stage(k+2) writes
// buf[(k-1)%3]; any wave issuing it passed barrier(k), and program order
// reads(k-1)->stage(k+1)->vmcnt->barrier(k) means ALL waves done reading).
// Round-12's register-direct (no LDS) variant regressed 451->538: LDS staging
// absorbs L2 latency + 4x fetch amplification; do NOT remove it.
// Plain __launch_bounds__(1024) — round-5's (1024,8) spilled acc. Never re-add.
__global__ __launch_bounds__(1024)
void gemmA(const unsigned short* __restrict__ xperm,
           const unsigned short* __restrict__ Wperm,
           const float* __restrict__ bias,
           const int* __restrict__ aidx,
           const unsigned short* __restrict__ tgtbf,
           float* __restrict__ Epad,
           const int* __restrict__ table, int nblk, int K,
           const int* __restrict__ pref,
           unsigned short* __restrict__ outs)
{
    __shared__ __align__(16) unsigned short sA[3][4096];     // 24KB
    __shared__ __align__(16) unsigned short sB[3][12288];    // 72KB
    __shared__ float sRow[128];
    __shared__ int sKK[TC];
    __shared__ int sSlot[TC];

    int bid = blockIdx.x;
    int q8 = nblk >> 3, r8 = nblk & 7;
    int xcd = bid & 7, pos = bid >> 3;
    int lb = (xcd < r8 ? xcd * (q8 + 1) : r8 * (q8 + 1) + (xcd - r8) * q8) + pos;

    int s = table[3 * lb], t0s = table[3 * lb + 1], cnt = table[3 * lb + 2];

    int tid = threadIdx.x;
    int wid = tid >> 6, lane = tid & 63;
    int waveM = wid >> 2, waveN = wid & 3;
    int lc = lane & 15, lg = lane >> 4;

    int tcl[4];
#pragma unroll
    for (int tc = 0; tc < 4; ++tc) { int t = t0s + tc; tcl[tc] = t > TT - 1 ? TT - 1 : t; }

    // slot/kk search in prologue (ordered by post-K-loop __syncthreads)
    if (tid < TC) {
        int kk = 0, slot = 0;
        if (tid < cnt) {
            int t = t0s + tid;
            for (int k2 = 0; k2 < K; ++k2)
                if (aidx[t * K + k2] == s) { kk = k2; break; }
            if (pref) slot = pref[t] + kk;
        }
        sKK[tid] = kk;
        sSlot[tid] = slot;
    }

    f32x4 acc[2][6];
    f32x4 zz = {0.f, 0.f, 0.f, 0.f};
#pragma unroll
    for (int m = 0; m < 2; ++m)
#pragma unroll
        for (int n = 0; n < 6; ++n) acc[m][n] = zz;

    const size_t wbase = (size_t)s * (12 * 24 * 512);

    // every wave issues exactly 2 global_load_lds per stage
    auto stage = [&](int buf, int ks) {
        if (wid < 8) {
            int tc = wid >> 1, bb = wid & 1;
            const unsigned short* asrc = xperm + ((size_t)tcl[tc] * 24 + bb * 12 + ks) * 512 + lane * 8;
            gl16(asrc, &sA[buf][wid * 512]);
            const unsigned short* bsrc = Wperm + wbase + ((size_t)ks * 24 + 16 + wid) * 512 + lane * 8;
            gl16(bsrc, &sB[buf][(16 + wid) * 512]);
        } else {
            int e0 = (wid - 8) * 2;
            const unsigned short* b0 = Wperm + wbase + ((size_t)ks * 24 + e0) * 512 + lane * 8;
            gl16(b0, &sB[buf][e0 * 512]);
            gl16(b0 + 512, &sB[buf][(e0 + 1) * 512]);
        }
    };

    // 3-buffer 2-ahead pipeline, ONE barrier per k-step
    stage(0, 0);
    stage(1, 1);
#pragma unroll
    for (int ks = 0; ks < 12; ++ks) {
        const int cur = ks % 3;
        if (ks < 11) asm volatile("s_waitcnt vmcnt(2)" ::: "memory");
        else         asm volatile("s_waitcnt vmcnt(0)" ::: "memory");
        __builtin_amdgcn_s_barrier();
        __builtin_amdgcn_sched_barrier(0);
        short8 af[2], bfr[6];
#pragma unroll
        for (int mf = 0; mf < 2; ++mf)
            af[mf] = *(const short8*)&sA[cur][(waveM * 2 + mf) * 512 + lane * 8];
#pragma unroll
        for (int nf = 0; nf < 6; ++nf)
            bfr[nf] = *(const short8*)&sB[cur][(waveN * 6 + nf) * 512 + lane * 8];
        __builtin_amdgcn_s_setprio(1);
#pragma unroll
        for (int mf = 0; mf < 2; ++mf)
#pragma unroll
            for (int nf = 0; nf < 6; ++nf)
                acc[mf][nf] = __builtin_amdgcn_mfma_f32_16x16x32_bf16(af[mf], bfr[nf], acc[mf][nf], 0, 0, 0);
        __builtin_amdgcn_s_setprio(0);
        __builtin_amdgcn_sched_barrier(0);
        if (ks < 10) stage((ks + 2) % 3, ks + 2);   // writes buf holding tile k-1
    }
    __syncthreads();

    // ---- epilogue (2-phase, stride-12 stats): bias -> outs -> psum/pdot -> E ----
    float* sStat = (float*)&sA[0][0];   // [128][12]: 0..3 psum, 4..7 pdot
#pragma unroll
    for (int nf = 0; nf < 6; ++nf) {
        float be = bias[(size_t)s * DD + waveN * 96 + nf * 16 + lc];
#pragma unroll
        for (int mf = 0; mf < 2; ++mf)
#pragma unroll
            for (int rr = 0; rr < 4; ++rr) acc[mf][nf][rr] += be;
    }
    // frag-packed outs store: per (mf,nf) one 8B uint2 at [slot][c2][lane]
    if (outs && waveM < cnt) {
        unsigned short* ob = outs + (size_t)sSlot[waveM] * 12288;
#pragma unroll
        for (int mf = 0; mf < 2; ++mf)
#pragma unroll
            for (int nf = 0; nf < 6; ++nf) {
                int c2 = mf * 24 + waveN * 6 + nf;
                unsigned int lo, hi;
                asm("v_cvt_pk_bf16_f32 %0, %1, %2" : "=v"(lo)
                    : "v"(acc[mf][nf][0]), "v"(acc[mf][nf][1]));
                asm("v_cvt_pk_bf16_f32 %0, %1, %2" : "=v"(hi)
                    : "v"(acc[mf][nf][2]), "v"(acc[mf][nf][3]));
                uint2 pk; pk.x = lo; pk.y = hi;
                *(uint2*)&ob[c2 * 256 + lane * 4] = pk;
            }
    }
    // psum/pdot without max-subtraction (outs ~ N(0,1): exp overflow impossible)
#pragma unroll
    for (int mf = 0; mf < 2; ++mf)
#pragma unroll
        for (int rr = 0; rr < 4; ++rr) {
            int row = waveM * 32 + mf * 16 + lg * 4 + rr;
            int tcr = row >> 5, b = row & 31;
            int t = tcl[tcr];
            const unsigned short* tg = tgtbf + ((size_t)b * TT + t) * DD;
            float psum = 0.f, pdot = 0.f;
#pragma unroll
            for (int nf = 0; nf < 6; ++nf) {
                int e = waveN * 96 + nf * 16 + lc;
                float a = acc[mf][nf][rr];
                psum += __expf(a);
                float tv = __uint_as_float(((unsigned int)tg[e]) << 16);
                pdot += tv * a;
            }
#pragma unroll
            for (int d = 1; d < 16; d <<= 1) { psum += __shfl_xor(psum, d); pdot += __shfl_xor(pdot, d); }
            if (lc == 0) { sStat[row * 12 + waveN] = psum; sStat[row * 12 + 4 + waveN] = pdot; }
        }
    __syncthreads();
    if (wid == 0) {
#pragma unroll
        for (int h = 0; h < 2; ++h) {
            int row = lane + h * 64;
            const f32x4 pp = *(const f32x4*)&sStat[row * 12];
            const f32x4 dd = *(const f32x4*)&sStat[row * 12 + 4];
            float S = pp[0] + pp[1] + pp[2] + pp[3];
            float Dt = dd[0] + dd[1] + dd[2] + dd[3];
            sRow[row] = __logf(S) - Dt;
        }
    }
    __syncthreads();
    if (wid == 0) {
#pragma unroll
        for (int pph = 0; pph < 2; ++pph) {
            int tc = pph * 2 + (lane >> 5);
            int b = lane & 31;
            float v = (tc < cnt) ? sRow[tc * 32 + b] : 0.f;
#pragma unroll
            for (int d = 1; d < 32; d <<= 1) v += __shfl_xor(v, d);
            if (b == 0 && tc < cnt) {
                float loss = v * (1.0f / 32.0f);
                float E = __expf(-ALPHA_ * loss);
                int t0 = t0s + tc;
                Epad[t0 * 32 + sKK[tc]] = E;
            }
        }
    }
}

// ---------------- recur3: LDS-staged serial recurrence ----------------
__global__ __launch_bounds__(256)
void recur3(const float* __restrict__ Epad, const short* __restrict__ perm16,
            const int* __restrict__ aidx, const float* __restrict__ amask,
            float* __restrict__ wraw, int K) {
    __shared__ __align__(16) float sE[2][4096];
    __shared__ __align__(16) short sP[2][4160];
    int tid = threadIdx.x, wid = tid >> 6, lane = tid & 63;
    int l = lane;

    auto stageCh = [&](int buf, int c) {
        const float* eb = Epad + c * 4096;
#pragma unroll
        for (int i = wid; i < 16; i += 4)
            gl16(eb + i * 256 + lane * 4, &sE[buf][i * 256]);
        const short* pb = perm16 + (c * 128 + 1) * 32;
#pragma unroll
        for (int i = wid; i < 8; i += 4)
            gl16(pb + i * 512 + lane * 8, &sP[buf][32 + i * 512]);
    };

    stageCh(0, 0);
    __syncthreads();

    float pr = 0.f;
    if (l < K && amask[l] > 0.f && aidx[l] == 0) pr = 1.f;

    int buf = 0;
    for (int c = 0; c < 8; ++c) {
        if (c < 7) stageCh(buf ^ 1, c + 1);
        if (wid == 0) {
            float curE = (l < 32) ? sE[buf][l] : 0.f;
            short curP = (l < 32) ? sP[buf][32 + l] : (short)63;
            for (int tl = 0; tl < 128; ++tl) {
                float nE = 0.f; short nP = 63;
                if (tl < 127) {
                    nE = sE[buf][(tl + 1) * 32 + (l & 31)];
                    nP = sP[buf][(tl + 2) * 32 + (l & 31)];
                }
                int t = c * 128 + tl;
                if (l < 32) wraw[t * 32 + l] = pr;
                float qv = pr * curE;
                float S2 = dppsum32(qv);
                float pn = qv / S2;
                int pe = (l < 32) ? (int)curP : 63;
                int src = pe >= 0 ? pe : 0;
                float sv = __shfl(pn, src);
                pr = (pe >= 0) ? sv : (1.0f / (float)(-pe));
                curE = (l < 32) ? nE : 0.f;
                curP = nP;
            }
        }
        __syncthreads();
        buf ^= 1;
    }
}

// ---------------- normalize wraw -> w (tier2 only) ----------------
__global__ void wnorm(float* __restrict__ w) {
    int tid = threadIdx.x;
    int wid = tid >> 6, lane = tid & 63;
    int half = lane >> 5, l = lane & 31;
    int t = blockIdx.x * 8 + wid * 2 + half;
    float v = w[t * 32 + l];
    float s = v;
#pragma unroll
    for (int d = 1; d < 32; d <<= 1) s += __shfl_xor(s, d);
    w[t * 32 + l] = v / s;
}

// ---------------- mixout (frag layout, fused weight-normalize) ----------------
__global__ __launch_bounds__(512)
void mixout(const unsigned short* __restrict__ outs, const float* __restrict__ wraw,
            const int* __restrict__ pref, float* __restrict__ y) {
    int t = blockIdx.x;
    __shared__ float sW[32];
    int tid = threadIdx.x;
    if (tid < 32) {
        float v = wraw[t * 32 + tid];       // dead lanes are exact 0
        float s = v;
#pragma unroll
        for (int d = 1; d < 32; d <<= 1) s += __shfl_xor(s, d);
        sW[tid] = v / s;
    }
    __syncthreads();
    int p0 = pref[t];
    int L = pref[t + 1] - p0;
    float acc[24];
#pragma unroll
    for (int i = 0; i < 24; ++i) acc[i] = 0.f;
    const ushort8* base = (const ushort8*)(outs + (size_t)p0 * 12288);
    for (int kk = 0; kk < L; ++kk) {
        float w = sW[kk];
        const ushort8* sp = base + (size_t)kk * 1536;
#pragma unroll
        for (int pass = 0; pass < 3; ++pass) {
            ushort8 v = sp[pass * 512 + tid];
#pragma unroll
            for (int j = 0; j < 8; ++j)
                acc[pass * 8 + j] += w * __uint_as_float(((unsigned int)v[j]) << 16);
        }
    }
    // decode frag layout: pos = idx*8+j; c2 = idx>>5; lane = (idx*2 + (j>>2))&63; rr = j&3
#pragma unroll
    for (int pass = 0; pass < 3; ++pass) {
        int idx = pass * 512 + tid;
        int c2 = idx >> 5;
        int lane0 = (idx * 2) & 63;
        int mf = (c2 >= 24) ? 1 : 0;
        int rem = c2 - mf * 24;
        int wN = rem / 6, nf = rem - wN * 6;
        int e0 = wN * 96 + nf * 16 + (lane0 & 15);      // lane0 even -> e0, e0+1 pair
        int bb = mf * 16 + (lane0 >> 4) * 4;
#pragma unroll
        for (int r = 0; r < 4; ++r) {
            int b = bb + r;
            float2 st;
            st.x = acc[pass * 8 + r];        // (b, e0)   from lane0
            st.y = acc[pass * 8 + 4 + r];    // (b, e0+1) from lane0+1
            *(float2*)&y[((size_t)b * TT + t) * DD + e0] = st;
        }
    }
}

// ================= tier2 helpers (round-3 verified) =================
__global__ void setup_blocks(int* __restrict__ table) {
    int j = threadIdx.x + 1;
    int L; int nc = chunks_of(j, &L);
    int start = 0;
    for (int jp = 1; jp < j; ++jp) { int Lp; start += chunks_of(jp, &Lp); }
    for (int c = 0; c < nc; ++c) {
        int cnt = L - c * TC; if (cnt > TC) cnt = TC;
        int* e = table + 3 * (start + c);
        e[0] = j - 1;
        e[1] = (j - 1) + c * TC;
        e[2] = cnt;
    }
}

__global__ void setup_union(int* __restrict__ uCount, int* __restrict__ uList) {
    int c = threadIdx.x;
    int t1 = 2 * c + 1, t2 = 2 * c + 2;
    int n = 0;
    for (int j = 1; j <= t2 && j <= TT; ++j) {
        int k = __builtin_ctz(j);
        int life = (1 << (k + 2)) + 1;
        if (j + life - 1 >= t1) { if (n < 32) uList[c * 32 + n] = j - 1; n++; }
    }
    uCount[c] = n > 32 ? 32 : n;
}

__global__ void setup_perm3(const int* __restrict__ aidx, const float* __restrict__ amask,
                            short* __restrict__ perm16, int K) {
    int t0 = blockIdx.x;
    int l = threadIdx.x;
    short enc = 63;
    if (t0 >= 1 && t0 <= TT - 1 && l < K && amask[t0 * K + l] > 0.f) {
        int sp = aidx[t0 * K + l];
        if (sp == t0) enc = (short)(-sp);
        else {
            for (int kk = 0; kk < K; ++kk)
                if (aidx[(t0 - 1) * K + kk] == sp) { enc = (short)kk; break; }
        }
    }
    perm16[t0 * 32 + l] = enc;
}

__global__ void conv_w(const float* __restrict__ W, unsigned short* __restrict__ Wperm) {
    int db = blockIdx.x;
    int j  = blockIdx.y;
    __shared__ __align__(16) unsigned short sL[12288];
    int tid = threadIdx.x;
    int r = tid >> 4, q = tid & 15;
    const float* src = W + (size_t)j * (DD * DD) + (size_t)(db * 32 + r) * DD + q * 24;
#pragma unroll
    for (int i = 0; i < 6; ++i) {
        float4 f = *(const float4*)(src + i * 4);
        int e0 = q * 24 + i * 4;
        float fv[4] = {f.x, f.y, f.z, f.w};
#pragma unroll
        for (int m = 0; m < 4; ++m) {
            int e = e0 + m;
            int off = (e >> 4) * 512 + (r >> 3) * 128 + (e & 15) * 8 + (r & 7);
            sL[off] = f2bf(fv[m]);
        }
    }
    __syncthreads();
    ushort8* dst = (ushort8*)(Wperm + ((size_t)j * 12 + db) * 12288);
    const ushort8* s8 = (const ushort8*)sL;
#pragma unroll
    for (int i = 0; i < 3; ++i) dst[tid * 3 + i] = s8[tid * 3 + i];
}

__global__ void conv_x(const float* __restrict__ x, unsigned short* __restrict__ xperm) {
    int t = blockIdx.x;
    __shared__ __align__(16) unsigned short sL[12288];
    int tid = threadIdx.x;
    int b = tid >> 4, q = tid & 15;
    const float* src = x + ((size_t)b * TT + t) * DD + q * 24;
#pragma unroll
    for (int i = 0; i < 6; ++i) {
        float4 f = *(const float4*)(src + i * 4);
        int d0 = q * 24 + i * 4;
        float fv[4] = {f.x, f.y, f.z, f.w};
#pragma unroll
        for (int m = 0; m < 4; ++m) {
            int d = d0 + m;
            int off = ((b >> 4) * 12 + (d >> 5)) * 512 + ((d >> 3) & 3) * 128 + (b & 15) * 8 + (d & 7);
            sL[off] = f2bf(fv[m]);
        }
    }
    __syncthreads();
    ushort8* dst = (ushort8*)(xperm + (size_t)t * 12288);
    const ushort8* s8 = (const ushort8*)sL;
#pragma unroll
    for (int i = 0; i < 3; ++i) dst[tid * 3 + i] = s8[tid * 3 + i];
}

__global__ __launch_bounds__(1024)
void gemmC(const unsigned short* __restrict__ xperm,
           const unsigned short* __restrict__ Wperm,
           const float* __restrict__ bias,
           const int* __restrict__ aidx,
           const float* __restrict__ wts32,
           const int* __restrict__ uCount, const int* __restrict__ uList,
           float* __restrict__ y, int K)
{
    __shared__ __align__(16) unsigned short sAF[24576];
    __shared__ __align__(16) unsigned short sB[2][12288];
    __shared__ float sWu[64];
    __shared__ int   sUL[32];
    __shared__ float sBv[768];

    int nb = gridDim.x;
    int bid = blockIdx.x;
    int q8 = nb >> 3, r8 = nb & 7;
    int xcd = bid & 7, pos = bid >> 3;
    int c = (xcd < r8 ? xcd * (q8 + 1) : r8 * (q8 + 1) + (xcd - r8) * q8) + pos;

    int t0 = c * 2;
    int tid = threadIdx.x, wid = tid >> 6, lane = tid & 63;
    int waveM = wid >> 2, waveN = wid & 3;
    int lc = lane & 15, lg = lane >> 4;
    int tcw = waveM >> 1, bbw = waveM & 1;

    int uc = uCount[c];
    if (tid < uc) sUL[tid] = uList[c * 32 + tid];
#pragma unroll
    for (int i = 0; i < 3; ++i) {
        int T = wid * 3 + i;
        int tc = T / 24, bb = (T / 12) & 1, db = T % 12;
        const unsigned short* src = xperm + ((size_t)(t0 + tc) * 24 + bb * 12 + db) * 512 + lane * 8;
        gl16(src, &sAF[T * 512]);
    }
    __syncthreads();
    if (tid < 2 * uc) {
        int u = tid >> 1, tc = tid & 1;
        int j = sUL[u];
        float wv = 0.f;
        for (int kk = 0; kk < K; ++kk)
            if (aidx[(t0 + tc) * K + kk] == j) { wv = wts32[(t0 + tc) * 32 + kk]; break; }
        sWu[u * 2 + tc] = wv;
    }
    __syncthreads();
    {
        size_t wb = (size_t)sUL[0] * (12 * 24 * 512);
        const unsigned short* b0 = Wperm + wb + (size_t)wid * 512 + lane * 8;
        gl16(b0, &sB[0][wid * 512]);
        if (wid < 8) {
            const unsigned short* b1 = Wperm + wb + (size_t)(16 + wid) * 512 + lane * 8;
            gl16(b1, &sB[0][(16 + wid) * 512]);
        }
    }
    for (int i = tid; i < 768; i += 1024) {
        int tc = (i >= 384) ? 1 : 0; int e = i - tc * 384;
        float a = 0.f;
        for (int u = 0; u < uc; ++u) a += sWu[u * 2 + tc] * bias[(size_t)sUL[u] * DD + e];
        sBv[i] = a;
    }
    __syncthreads();

    f32x4 accY[6], accE[6];
    f32x4 zz = {0.f, 0.f, 0.f, 0.f};
#pragma unroll
    for (int n = 0; n < 6; ++n) { accY[n] = zz; accE[n] = zz; }

    int buf = 0;
    for (int u = 0; u < uc; ++u) {
        float wv = sWu[u * 2 + tcw];
        bool act = (wv != 0.f);
        for (int ks = 0; ks < 12; ++ks) {
            int nu = u, nk = ks + 1;
            if (nk == 12) { nk = 0; nu = u + 1; }
            if (nu < uc) {
                size_t wb = (size_t)sUL[nu] * (12 * 24 * 512) + (size_t)nk * (24 * 512);
                const unsigned short* b0 = Wperm + wb + (size_t)wid * 512 + lane * 8;
                gl16(b0, &sB[buf ^ 1][wid * 512]);
                if (wid < 8) {
                    const unsigned short* b1 = Wperm + wb + (size_t)(16 + wid) * 512 + lane * 8;
                    gl16(b1, &sB[buf ^ 1][(16 + wid) * 512]);
                }
            }
            if (act) {
                short8 af = *(const short8*)&sAF[(waveM * 12 + ks) * 512 + lane * 8];
#pragma unroll
                for (int nf = 0; nf < 6; ++nf) {
                    short8 bf = *(const short8*)&sB[buf][(waveN * 6 + nf) * 512 + lane * 8];
                    accE[nf] = __builtin_amdgcn_mfma_f32_16x16x32_bf16(af, bf, accE[nf], 0, 0, 0);
                }
            }
            __syncthreads();
            buf ^= 1;
        }
        if (act) {
#pragma unroll
            for (int nf = 0; nf < 6; ++nf)
#pragma unroll
                for (int rr = 0; rr < 4; ++rr) { accY[nf][rr] += wv * accE[nf][rr]; accE[nf][rr] = 0.f; }
        }
    }

    int t = t0 + tcw;
#pragma unroll
    for (int nf = 0; nf < 6; ++nf) {
        int e = waveN * 96 + nf * 16 + lc;
        float bvv = sBv[tcw * 384 + e];
#pragma unroll
        for (int rr = 0; rr < 4; ++rr) {
            int b = bbw * 16 + lg * 4 + rr;
            y[((size_t)b * TT + t) * DD + e] = accY[nf][rr] + bvv;
        }
    }
}

// ================= tier3 fallback (round-1, verified) =================
__global__ void rowstats(const float* __restrict__ x, float* __restrict__ xm,
                         float* __restrict__ rz) {
    int wid = threadIdx.x >> 6;
    int lane = threadIdx.x & 63;
    int row = blockIdx.x * 4 + wid;
    const float* xr = x + (size_t)row * DD;
    float v[6];
    float m = -1e30f;
#pragma unroll
    for (int i = 0; i < 6; ++i) { v[i] = xr[lane + 64 * i]; m = fmaxf(m, v[i]); }
#pragma unroll
    for (int d = 1; d < 64; d <<= 1) m = fmaxf(m, __shfl_xor(m, d));
    float s = 0.f;
#pragma unroll
    for (int i = 0; i < 6; ++i) s += expf(v[i] - m);
#pragma unroll
    for (int d = 1; d < 64; d <<= 1) s += __shfl_xor(s, d);
    if (lane == 0) { xm[row] = m; rz[row] = 1.0f / s; }
}

template<int MODE>
__global__ __launch_bounds__(NTHR)
void gemm_phase(const float* __restrict__ x, const float* __restrict__ W,
                const float* __restrict__ bias, const int* __restrict__ aidx,
                const float* __restrict__ xm, const float* __restrict__ rz,
                const float* __restrict__ wts, float* __restrict__ Earr,
                float* __restrict__ y, const int* __restrict__ table,
                int nblk, int K)
{
    __shared__ __align__(16) unsigned short sA[MROWS * PADK];
    __shared__ __align__(16) unsigned short sB[DD * PADK];
    __shared__ float sRow[MROWS];
    __shared__ float sCoef[TC];

    int bid = blockIdx.x;
    int q = nblk >> 3, r = nblk & 7;
    int xcd = bid & 7, pos = bid >> 3;
    int lb = (xcd < r ? xcd * (q + 1) : r * (q + 1) + (xcd - r) * q) + pos;

    int s = table[3 * lb], t0s = table[3 * lb + 1], cnt = table[3 * lb + 2];

    int tid = threadIdx.x;
    int wid = tid >> 6, lane = tid & 63;
    int waveM = wid >> 2, waveN = wid & 3;
    int lc = lane & 15, lg = lane >> 4;

    if (MODE == 1 && tid < TC) {
        float c = 0.f;
        if (tid < cnt) {
            int t0 = t0s + tid;
            for (int kk = 0; kk < K; ++kk)
                if (aidx[t0 * K + kk] == s) { c = wts[t0 * K + kk]; break; }
        }
        sCoef[tid] = c;
    }

    f32x4 acc[4][6];
    f32x4 zz = {0.f, 0.f, 0.f, 0.f};
#pragma unroll
    for (int i = 0; i < 4; ++i)
#pragma unroll
        for (int n = 0; n < 6; ++n) acc[i][n] = zz;

    const float* Wj = W + (size_t)s * (DD * DD);

    int xr = tid >> 2, xq = tid & 3;
    int xtc = xr >> 5, xb = xr & 31;
    int xt = t0s + xtc; if (xt > TT - 1) xt = TT - 1;
    const float* xrow = x + ((size_t)xb * TT + xt) * DD;

    for (int ks = 0; ks < NKS; ++ks) {
        const int d0 = ks * KSTEP;
        __syncthreads();
        {
            const float4* src = (const float4*)(xrow + d0 + xq * 16);
            float4 f0 = src[0], f1 = src[1], f2 = src[2], f3 = src[3];
            short8 v0, v1;
            v0[0] = (short)f2bf(f0.x); v0[1] = (short)f2bf(f0.y);
            v0[2] = (short)f2bf(f0.z); v0[3] = (short)f2bf(f0.w);
            v0[4] = (short)f2bf(f1.x); v0[5] = (short)f2bf(f1.y);
            v0[6] = (short)f2bf(f1.z); v0[7] = (short)f2bf(f1.w);
            v1[0] = (short)f2bf(f2.x); v1[1] = (short)f2bf(f2.y);
            v1[2] = (short)f2bf(f2.z); v1[3] = (short)f2bf(f2.w);
            v1[4] = (short)f2bf(f3.x); v1[5] = (short)f2bf(f3.y);
            v1[6] = (short)f2bf(f3.z); v1[7] = (short)f2bf(f3.w);
            short8* dst = (short8*)&sA[xr * PADK + xq * 16];
            dst[0] = v0; dst[1] = v1;
        }
        {
            int dbase = d0 + wid * 8;
#pragma unroll
            for (int g = 0; g < 6; ++g) {
                int e = g * 64 + lane;
                const float* col = Wj + (size_t)dbase * DD + e;
                short8 h;
#pragma unroll
                for (int dd = 0; dd < 8; ++dd) h[dd] = (short)f2bf(col[(size_t)dd * DD]);
                *(short8*)&sB[e * PADK + wid * 8] = h;
            }
        }
        __syncthreads();
#pragma unroll
        for (int kh = 0; kh < 2; ++kh) {
            short8 af[4], bfr[6];
#pragma unroll
            for (int mf = 0; mf < 4; ++mf)
                af[mf] = *(const short8*)&sA[(waveM * 64 + mf * 16 + lc) * PADK + kh * 32 + lg * 8];
#pragma unroll
            for (int nf = 0; nf < 6; ++nf)
                bfr[nf] = *(const short8*)&sB[(waveN * 96 + nf * 16 + lc) * PADK + kh * 32 + lg * 8];
#pragma unroll
            for (int mf = 0; mf < 4; ++mf)
#pragma unroll
                for (int nf = 0; nf < 6; ++nf)
                    acc[mf][nf] = __builtin_amdgcn_mfma_f32_16x16x32_bf16(af[mf], bfr[nf], acc[mf][nf], 0, 0, 0);
        }
    }

    if (MODE == 0) {
        __syncthreads();
        float* sStat = (float*)sA;
#pragma unroll
        for (int nf = 0; nf < 6; ++nf) {
            float be = bias[(size_t)s * DD + waveN * 96 + nf * 16 + lc];
#pragma unroll
            for (int mf = 0; mf < 4; ++mf)
#pragma unroll
                for (int rr = 0; rr < 4; ++rr) acc[mf][nf][rr] += be;
        }
#pragma unroll
        for (int mf = 0; mf < 4; ++mf)
#pragma unroll
            for (int rr = 0; rr < 4; ++rr) {
                float m = acc[mf][0][rr];
#pragma unroll
                for (int nf = 1; nf < 6; ++nf) m = fmaxf(m, acc[mf][nf][rr]);
#pragma unroll
                for (int d = 1; d < 16; d <<= 1) m = fmaxf(m, __shfl_xor(m, d));
                if (lc == 0) sStat[(waveM * 64 + mf * 16 + lg * 4 + rr) * 12 + waveN] = m;
            }
        __syncthreads();
#pragma unroll
        for (int mf = 0; mf < 4; ++mf)
#pragma unroll
            for (int rr = 0; rr < 4; ++rr) {
                int row = waveM * 64 + mf * 16 + lg * 4 + rr;
                const f32x4 pm = *(const f32x4*)&sStat[row * 12];
                float rmax = fmaxf(fmaxf(pm[0], pm[1]), fmaxf(pm[2], pm[3]));
                int tc = row >> 5, b = row & 31;
                int t = t0s + tc; if (t > TT - 1) t = TT - 1;
                float xmv = xm[b * TT + t];
                float rzv = rz[b * TT + t];
                const float* x2 = x + ((size_t)b * TT + t) * DD;
                float psum = 0.f, pdot = 0.f;
#pragma unroll
                for (int nf = 0; nf < 6; ++nf) {
                    int e = waveN * 96 + nf * 16 + lc;
                    float a = acc[mf][nf][rr];
                    psum += __expf(a - rmax);
                    float tg = __expf(x2[e] - xmv) * rzv;
                    pdot += tg * a;
                }
#pragma unroll
                for (int d = 1; d < 16; d <<= 1) {
                    psum += __shfl_xor(psum, d);
                    pdot += __shfl_xor(pdot, d);
                }
                if (lc == 0) { sStat[row * 12 + 4 + waveN] = psum; sStat[row * 12 + 8 + waveN] = pdot; }
            }
        __syncthreads();
        if (wid == 0) {
#pragma unroll
            for (int h = 0; h < 2; ++h) {
                int row = lane + h * 64;
                const f32x4 mm = *(const f32x4*)&sStat[row * 12];
                const f32x4 pp = *(const f32x4*)&sStat[row * 12 + 4];
                const f32x4 dd = *(const f32x4*)&sStat[row * 12 + 8];
                float rmax = fmaxf(fmaxf(mm[0], mm[1]), fmaxf(mm[2], mm[3]));
                float S = pp[0] + pp[1] + pp[2] + pp[3];
                float Dt = dd[0] + dd[1] + dd[2] + dd[3];
                sRow[row] = rmax + logf(S) - Dt;
            }
        }
        __syncthreads();
        if (wid == 0) {
#pragma unroll
            for (int pph = 0; pph < 2; ++pph) {
                int tc = pph * 2 + (lane >> 5);
                int b = lane & 31;
                float v = (tc < cnt) ? sRow[tc * 32 + b] : 0.f;
#pragma unroll
                for (int d = 1; d < 32; d <<= 1) v += __shfl_xor(v, d);
                if (b == 0 && tc < cnt) {
                    float loss = v * (1.0f / 32.0f);
                    float E = expf(-ALPHA_ * loss);
                    int t0 = t0s + tc;
                    for (int kk = 0; kk < K; ++kk)
                        if (aidx[t0 * K + kk] == s) { Earr[t0 * K + kk] = E; break; }
                }
            }
        }
    } else {
#pragma unroll
        for (int mf = 0; mf < 4; ++mf)
#pragma unroll
            for (int rr = 0; rr < 4; ++rr) {
                int row = waveM * 64 + mf * 16 + lg * 4 + rr;
                int tc = row >> 5, b = row & 31;
                if (tc < cnt) {
                    float c = sCoef[tc];
                    int t = t0s + tc;
                    float* yr = y + ((size_t)b * TT + t) * DD + waveN * 96 + lc;
#pragma unroll
                    for (int nf = 0; nf < 6; ++nf)
                        atomicAdd(yr + nf * 16, c * acc[mf][nf][rr]);
                }
            }
    }
}

__global__ void recurrence(const int* __restrict__ aidx, const float* __restrict__ amask,
                           const float* __restrict__ Earr, float* __restrict__ wts, int K) {
    __shared__ float p[NE];
    int l = threadIdx.x;
    for (int i = l; i < NE; i += 64) p[i] = 0.f;
    __syncthreads();
    if (l == 0) p[0] = 1.f;
    __syncthreads();

    int idxv = TT; float mv = 0.f, Ev = 1.f;
    if (l < K) { idxv = aidx[l]; mv = amask[l]; Ev = Earr[l]; }

    for (int t0 = 0; t0 < TT; ++t0) {
        int idxn = TT; float mn = 0.f, En = 1.f;
        if (t0 + 1 < TT && l < K) {
            idxn = aidx[(t0 + 1) * K + l];
            mn = amask[(t0 + 1) * K + l];
            En = Earr[(t0 + 1) * K + l];
        }
        float pa = (l < K) ? p[idxv] * mv : 0.f;
        float qv = pa * Ev;
        float S1 = pa, S2 = qv;
#pragma unroll
        for (int d = 1; d < 64; d <<= 1) {
            S1 += __shfl_xor(S1, d);
            S2 += __shfl_xor(S2, d);
        }
        float w = pa / S1;
        if (l < K) wts[t0 * K + l] = w;
        float pn = qv / S2;
        __syncthreads();
        if (l < K && mv > 0.f) p[idxv] = pn;
        if (l == 0) p[t0 + 1] = 1.0f / (float)(t0 + 1);
        __syncthreads();
        idxv = idxn; mv = mn; Ev = En;
    }
}

__global__ void bias_init(const float* __restrict__ bias, const int* __restrict__ aidx,
                          const float* __restrict__ wts, float* __restrict__ y, int K) {
    int t0 = blockIdx.x;
    int e = threadIdx.x;
    float acc = 0.f;
    for (int kk = 0; kk < K; ++kk) {
        float w = wts[t0 * K + kk];
        int s = aidx[t0 * K + kk];
        acc += w * bias[(size_t)s * DD + e];
    }
    for (int b = 0; b < BB; ++b)
        y[((size_t)b * TT + t0) * DD + e] = acc;
}

extern "C" void kernel_launch(void* const* d_in, const int* in_sizes, int n_in,
                              void* d_out, int out_size, void* d_ws, size_t ws_size,
                              hipStream_t stream) {
    const float* x = (const float*)d_in[0];
    const float* W = (const float*)d_in[1];
    const float* bv = (const float*)d_in[2];
    const int* aidx = (const int*)d_in[3];
    const float* amask = (const float*)d_in[4];
    float* y = (float*)d_out;
    const int K = in_sizes[3] / TT;

    int nblk = 0, NSLOT = 0;
    for (int j = 1; j <= TT; ++j) { int L; nblk += chunks_of(j, &L); NSLOT += L; }

    size_t szW = (size_t)1024 * 294912;
    size_t szX = (size_t)1024 * 24576;
    size_t szT = (size_t)BB * TT * DD * 2;
    size_t szEp = (size_t)TT * 32 * sizeof(float);
    size_t szWt = (size_t)TT * 32 * sizeof(float);
    size_t szPm = (size_t)(TT + 1) * 32 * sizeof(short);
    size_t szTab = (size_t)6144 * 3 * sizeof(int);
    size_t szUC = 512 * sizeof(int);
    size_t szUL = 512 * 32 * sizeof(int);
    size_t szO  = (size_t)NSLOT * 12288 * 2;
    size_t szPf = (size_t)(TT + 1) * sizeof(int);
    size_t need2 = szW + szX + szT + szEp + szWt + szPm + szTab + szUC + szUL + 256;
    size_t need1 = need2 + szO + szPf;

    if (ws_size >= need1) {
        // ---- tier1 ----
        unsigned char* p = (unsigned char*)d_ws;
        unsigned short* Wperm = (unsigned short*)p; p += szW;
        unsigned short* xperm = (unsigned short*)p; p += szX;
        unsigned short* tgtb  = (unsigned short*)p; p += szT;
        float* Epad = (float*)p; p += szEp;
        float* wts32 = (float*)p; p += szWt;
        short* perm16 = (short*)p; p += szPm;
        int* table  = (int*)p;   p += szTab;
        int* uCnt   = (int*)p;   p += szUC;
        int* uLst   = (int*)p;   p += szUL;
        int* pref   = (int*)p;   p += szPf;
        unsigned short* outs = (unsigned short*)p; p += szO;

        hipLaunchKernelGGL(setup_all, dim3(TT + 3), dim3(1024), 0, stream,
                           table, pref, perm16, aidx, amask, K);
        hipLaunchKernelGGL(conv_w2, dim3(12, 1024), dim3(512), 0, stream, W, Wperm);
        hipLaunchKernelGGL(conv_xt, dim3(TT + BB * TT / 8), dim3(512), 0, stream,
                           x, xperm, tgtb);
        hipMemsetAsync(Epad, 0, szEp, stream);
        hipLaunchKernelGGL(gemmA, dim3(nblk), dim3(1024), 0, stream,
                           xperm, Wperm, bv, aidx, tgtb, Epad, table, nblk, K, pref, outs);
        hipLaunchKernelGGL(recur3, dim3(1), dim3(256), 0, stream,
                           Epad, perm16, aidx, amask, wts32, K);
        hipLaunchKernelGGL(mixout, dim3(TT), dim3(512), 0, stream, outs, wts32, pref, y);
    } else if (ws_size >= need2) {
        // ---- tier2 ----
        unsigned char* p = (unsigned char*)d_ws;
        unsigned short* Wperm = (unsigned short*)p; p += szW;
        unsigned short* xperm = (unsigned short*)p; p += szX;
        unsigned short* tgtb  = (unsigned short*)p; p += szT;
        float* Epad = (float*)p; p += szEp;
        float* wts32 = (float*)p; p += szWt;
        short* perm16 = (short*)p; p += szPm;
        int* table  = (int*)p;   p += szTab;
        int* uCnt   = (int*)p;   p += szUC;
        int* uLst   = (int*)p;   p += szUL;

        hipLaunchKernelGGL(setup_blocks, dim3(1), dim3(1024), 0, stream, table);
        hipLaunchKernelGGL(setup_union, dim3(1), dim3(512), 0, stream, uCnt, uLst);
        hipLaunchKernelGGL(setup_perm3, dim3(TT + 1), dim3(32), 0, stream, aidx, amask, perm16, K);
        hipLaunchKernelGGL(conv_w, dim3(12, 1024), dim3(512), 0, stream, W, Wperm);
        hipLaunchKernelGGL(conv_x, dim3(TT), dim3(512), 0, stream, x, xperm);
        hipLaunchKernelGGL(conv_tgt, dim3(BB * TT / 8), dim3(512), 0, stream, x, tgtb);
        hipMemsetAsync(Epad, 0, szEp, stream);
        hipLaunchKernelGGL(gemmA, dim3(nblk), dim3(1024), 0, stream,
                           xperm, Wperm, bv, aidx, tgtb, Epad, table, nblk, K,
                           (const int*)nullptr, (unsigned short*)nullptr);
        hipLaunchKernelGGL(recur3, dim3(1), dim3(256), 0, stream,
                           Epad, perm16, aidx, amask, wts32, K);
        hipLaunchKernelGGL(wnorm, dim3(TT / 8), dim3(256), 0, stream, wts32);
        hipLaunchKernelGGL(gemmC, dim3(512), dim3(1024), 0, stream,
                           xperm, Wperm, bv, aidx, wts32, uCnt, uLst, y, K);
    } else {
        // ---- tier3 ----
        float* Earr = (float*)d_ws;
        float* wts = Earr + (size_t)TT * K;
        float* xm = wts + (size_t)TT * K;
        float* rz = xm + (size_t)BB * TT;
        int* table = (int*)(rz + (size_t)BB * TT);

        hipLaunchKernelGGL(setup_blocks, dim3(1), dim3(1024), 0, stream, table);
        hipLaunchKernelGGL(rowstats, dim3(BB * TT / 4), dim3(256), 0, stream, x, xm, rz);
        hipLaunchKernelGGL((gemm_phase<0>), dim3(nblk), dim3(NTHR), 0, stream,
                           x, W, bv, aidx, xm, rz, (const float*)nullptr, Earr,
                           (float*)nullptr, table, nblk, K);
        hipLaunchKernelGGL(recurrence, dim3(1), dim3(64), 0, stream, aidx, amask, Earr, wts, K);
        hipLaunchKernelGGL(bias_init, dim3(TT), dim3(DD), 0, stream, bv, aidx, wts, y, K);
        hipLaunchKernelGGL((gemm_phase<1>), dim3(nblk), dim3(NTHR), 0, stream,
                           x, W, bv, aidx, xm, rz, wts, (float*)nullptr, y, table, nblk, K);
    }
}